// Round 1
// baseline (1799.592 us; speedup 1.0000x reference)
//
#include <hip/hip_runtime.h>
#include <math.h>

#define BATCH 16
#define CDIM 384
#define HH 32
#define WW 32
#define NPIX 1024            // 32*32
#define MTOK (BATCH * NPIX)  // 16384
#define NHEADS 8
#define DH 48
#define QKVN (3 * CDIM)      // 1152
#define FFN (4 * CDIM)       // 1536

// ---------------------------------------------------------------------------
// 1) depthwise 3x3 conv + center + pos bias, written transposed to t[(b*N+p)*C+c]
// ---------------------------------------------------------------------------
__global__ void conv_pe_kernel(const float* __restrict__ x,
                               const float* __restrict__ pos_w,
                               const float* __restrict__ pos_b,
                               float* __restrict__ t) {
    int bc = blockIdx.x;                 // b*CDIM + c
    int b = bc / CDIM, c = bc % CDIM;
    const float* xp = x + (size_t)bc * NPIX;
    float w[9];
#pragma unroll
    for (int i = 0; i < 9; ++i) w[i] = pos_w[c * 9 + i];
    float pb = pos_b[c];
    for (int p = threadIdx.x; p < NPIX; p += blockDim.x) {
        int h = p >> 5, wq = p & 31;
        float acc = 0.f;
#pragma unroll
        for (int kh = 0; kh < 3; ++kh) {
            int hh = h + kh - 1;
            if (hh < 0 || hh >= HH) continue;
#pragma unroll
            for (int kw = 0; kw < 3; ++kw) {
                int ww2 = wq + kw - 1;
                if (ww2 < 0 || ww2 >= WW) continue;
                acc += xp[hh * WW + ww2] * w[kh * 3 + kw];
            }
        }
        float v = xp[p] + acc + pb;
        t[(size_t)(b * NPIX + p) * CDIM + c] = v;
    }
}

// ---------------------------------------------------------------------------
// 2) row LayerNorm over C=384. 128 threads/row, 3 elems/thread.
// ---------------------------------------------------------------------------
__global__ void ln_kernel(const float* __restrict__ in,
                          const float* __restrict__ g,
                          const float* __restrict__ bta,
                          float* __restrict__ out) {
    int m = blockIdx.x;
    const float* row = in + (size_t)m * CDIM;
    int tid = threadIdx.x;  // 0..127
    float v0 = row[tid], v1 = row[tid + 128], v2 = row[tid + 256];
    float s = v0 + v1 + v2;
    float ss = v0 * v0 + v1 * v1 + v2 * v2;
#pragma unroll
    for (int off = 32; off > 0; off >>= 1) {
        s += __shfl_down(s, off, 64);
        ss += __shfl_down(ss, off, 64);
    }
    __shared__ float red[4];
    if ((tid & 63) == 0) { red[tid >> 6] = s; red[2 + (tid >> 6)] = ss; }
    __syncthreads();
    float sum = red[0] + red[1], sumsq = red[2] + red[3];
    float mu = sum * (1.f / CDIM);
    float var = sumsq * (1.f / CDIM) - mu * mu;
    float rstd = rsqrtf(var + 1e-5f);
    float* orow = out + (size_t)m * CDIM;
    orow[tid]       = (v0 - mu) * rstd * g[tid]       + bta[tid];
    orow[tid + 128] = (v1 - mu) * rstd * g[tid + 128] + bta[tid + 128];
    orow[tid + 256] = (v2 - mu) * rstd * g[tid + 256] + bta[tid + 256];
}

// ---------------------------------------------------------------------------
// 3) fp32 tiled GEMM: C = A[MxK] * B[KxN] + bias (+Res) (+GELU)
//    BM=BN=64, BK=16, 256 threads, 4x4 microtile per thread.
// ---------------------------------------------------------------------------
template <int RES, int ACT>
__global__ __launch_bounds__(256) void gemm_kernel(
    const float* __restrict__ A, const float* __restrict__ B,
    const float* __restrict__ bias, const float* __restrict__ Res,
    float* __restrict__ C, int M, int N, int K) {
    __shared__ __align__(16) float As[16][80];  // [k][m], padded row 80 (16B-mult)
    __shared__ __align__(16) float Bs[16][64];  // [k][n]

    const int tid = threadIdx.x;
    const int m0 = blockIdx.y * 64;
    const int n0 = blockIdx.x * 64;

    // load mapping
    const int ar = tid >> 2;          // 0..63 (A row)
    const int ak = (tid & 3) * 4;     // 0,4,8,12
    const int bk = tid >> 4;          // 0..15 (B row)
    const int bn = (tid & 15) * 4;    // 0..60

    // compute mapping
    const int ty4 = (tid >> 4) * 4;   // acc rows
    const int tx4 = (tid & 15) * 4;   // acc cols

    const float* Aptr = A + (size_t)(m0 + ar) * K + ak;
    const float* Bptr = B + (size_t)bk * N + n0 + bn;

    float acc[4][4];
#pragma unroll
    for (int i = 0; i < 4; ++i)
#pragma unroll
        for (int j = 0; j < 4; ++j) acc[i][j] = 0.f;

    for (int k0 = 0; k0 < K; k0 += 16) {
        float4 av = *(const float4*)(Aptr + k0);
        float4 bv = *(const float4*)(Bptr + (size_t)k0 * N);
        __syncthreads();
        As[ak + 0][ar] = av.x;
        As[ak + 1][ar] = av.y;
        As[ak + 2][ar] = av.z;
        As[ak + 3][ar] = av.w;
        *(float4*)&Bs[bk][bn] = bv;
        __syncthreads();
#pragma unroll
        for (int kk = 0; kk < 16; ++kk) {
            float4 a = *(const float4*)&As[kk][ty4];
            float4 b = *(const float4*)&Bs[kk][tx4];
            float am[4] = {a.x, a.y, a.z, a.w};
            float bm[4] = {b.x, b.y, b.z, b.w};
#pragma unroll
            for (int i = 0; i < 4; ++i)
#pragma unroll
                for (int j = 0; j < 4; ++j) acc[i][j] += am[i] * bm[j];
        }
    }

    // epilogue
    float bb[4];
#pragma unroll
    for (int j = 0; j < 4; ++j) bb[j] = bias[n0 + tx4 + j];
#pragma unroll
    for (int i = 0; i < 4; ++i) {
        int m = m0 + ty4 + i;
        float4 ov;
        float o[4];
#pragma unroll
        for (int j = 0; j < 4; ++j) {
            float c = acc[i][j] + bb[j];
            if (RES) c += Res[(size_t)m * N + n0 + tx4 + j];
            if (ACT) c = 0.5f * c * (1.f + erff(c * 0.70710678118654752f));
            o[j] = c;
        }
        ov.x = o[0]; ov.y = o[1]; ov.z = o[2]; ov.w = o[3];
        *(float4*)(C + (size_t)m * N + n0 + tx4) = ov;
    }
}

// ---------------------------------------------------------------------------
// 4) attention: block = (query-tile 64, head, batch); 256 threads = 64 rows x 4.
//    Online softmax; per-thread partial O over its 16-key slice; quad-reduce.
// ---------------------------------------------------------------------------
__global__ __launch_bounds__(256) void attn_kernel(const float* __restrict__ qkv,
                                                   float* __restrict__ o) {
    const int qt = blockIdx.x;  // 0..15
    const int h = blockIdx.y;   // 0..7
    const int b = blockIdx.z;   // 0..15
    const int tid = threadIdx.x;
    const int r = tid >> 2;     // query row in tile 0..63
    const int cq = tid & 3;     // quad lane

    __shared__ __align__(16) float Ks[64][48];
    __shared__ __align__(16) float Vs[64][48];

    const float* base = qkv + (size_t)b * NPIX * QKVN + h * DH;

    float q[48];
    const float* qrow = base + (size_t)(qt * 64 + r) * QKVN;
#pragma unroll
    for (int d = 0; d < 48; ++d) q[d] = qrow[d];

    const float scale = 0.14433756729740643f;  // 1/sqrt(48)
    float oacc[48];
#pragma unroll
    for (int d = 0; d < 48; ++d) oacc[d] = 0.f;
    float mi = -1e30f, li = 0.f;

    for (int kt = 0; kt < 16; ++kt) {
        __syncthreads();
        for (int idx = tid; idx < 64 * 48; idx += 256) {
            int j = idx / 48, d = idx - j * 48;
            const float* kv = base + (size_t)(kt * 64 + j) * QKVN;
            Ks[j][d] = kv[CDIM + d];
            Vs[j][d] = kv[2 * CDIM + d];
        }
        __syncthreads();

        float sv[16];
        float tmax = -1e30f;
#pragma unroll
        for (int jj = 0; jj < 16; ++jj) {
            int j = (jj << 2) | cq;
            float s = 0.f;
#pragma unroll
            for (int d = 0; d < 48; ++d) s += q[d] * Ks[j][d];
            s *= scale;
            sv[jj] = s;
            tmax = fmaxf(tmax, s);
        }
        tmax = fmaxf(tmax, __shfl_xor(tmax, 1, 64));
        tmax = fmaxf(tmax, __shfl_xor(tmax, 2, 64));
        float newm = fmaxf(mi, tmax);
        float alpha = __expf(mi - newm);
        mi = newm;
        float lsum = 0.f;
#pragma unroll
        for (int jj = 0; jj < 16; ++jj) {
            float p = __expf(sv[jj] - newm);
            sv[jj] = p;
            lsum += p;
        }
        lsum += __shfl_xor(lsum, 1, 64);
        lsum += __shfl_xor(lsum, 2, 64);
        li = li * alpha + lsum;
#pragma unroll
        for (int d = 0; d < 48; ++d) oacc[d] *= alpha;
#pragma unroll
        for (int jj = 0; jj < 16; ++jj) {
            int j = (jj << 2) | cq;
            float p = sv[jj];
#pragma unroll
            for (int d = 0; d < 48; ++d) oacc[d] += p * Vs[j][d];
        }
    }

    // reduce partial O across the quad (all 4 lanes end with the full sum)
#pragma unroll
    for (int d = 0; d < 48; ++d) {
        oacc[d] += __shfl_xor(oacc[d], 1, 64);
        oacc[d] += __shfl_xor(oacc[d], 2, 64);
    }
    float inv = 1.f / li;
    float* orow = o + (size_t)(b * NPIX + qt * 64 + r) * CDIM + h * DH + cq * 12;
#pragma unroll
    for (int i = 0; i < 12; ++i) orow[i] = oacc[cq * 12 + i] * inv;
}

// ---------------------------------------------------------------------------
// 5) transpose (M,C) -> (B,C,H,W)
// ---------------------------------------------------------------------------
__global__ void transpose_kernel(const float* __restrict__ t, float* __restrict__ out) {
    __shared__ float tile[32][33];
    int b = blockIdx.z;
    int n0 = blockIdx.x * 32;
    int c0 = blockIdx.y * 32;
    int tx = threadIdx.x & 31;
    int ty = threadIdx.x >> 5;  // 0..7
    for (int i = ty; i < 32; i += 8)
        tile[i][tx] = t[(size_t)(b * NPIX + n0 + i) * CDIM + c0 + tx];
    __syncthreads();
    for (int i = ty; i < 32; i += 8)
        out[(size_t)(b * CDIM + c0 + i) * NPIX + n0 + tx] = tile[tx][i];
}

// ---------------------------------------------------------------------------
extern "C" void kernel_launch(void* const* d_in, const int* in_sizes, int n_in,
                              void* d_out, int out_size, void* d_ws, size_t ws_size,
                              hipStream_t stream) {
    const float* x = (const float*)d_in[0];
    const float* pos_w = (const float*)d_in[1];
    const float* pos_b = (const float*)d_in[2];
    const float* g1 = (const float*)d_in[3];
    const float* b1 = (const float*)d_in[4];
    const float* wqkv = (const float*)d_in[5];
    const float* bqkv = (const float*)d_in[6];
    const float* wproj = (const float*)d_in[7];
    const float* bproj = (const float*)d_in[8];
    const float* g2 = (const float*)d_in[9];
    const float* b2 = (const float*)d_in[10];
    const float* w1 = (const float*)d_in[11];
    const float* bf1 = (const float*)d_in[12];
    const float* w2 = (const float*)d_in[13];
    const float* bf2 = (const float*)d_in[14];
    float* out = (float*)d_out;

    // workspace layout (floats): t | xn/yn | big(qkv, o)  -- h reuses big
    float* ws = (float*)d_ws;
    float* t = ws;                                    // MTOK*384
    float* xn = ws + (size_t)MTOK * CDIM;             // MTOK*384
    float* big = ws + (size_t)2 * MTOK * CDIM;        // MTOK*1536
    float* qkvb = big;                                // MTOK*1152
    float* ob = big + (size_t)MTOK * QKVN;            // MTOK*384
    float* hb = big;                                  // MTOK*1536 (after attn+proj)

    // 1) conv positional encoding + transpose to (M, C)
    conv_pe_kernel<<<dim3(BATCH * CDIM), 256, 0, stream>>>(x, pos_w, pos_b, t);
    // 2) LN1
    ln_kernel<<<dim3(MTOK), 128, 0, stream>>>(t, g1, b1, xn);
    // 3) qkv = xn @ wqkv + bqkv
    gemm_kernel<0, 0><<<dim3(QKVN / 64, MTOK / 64), 256, 0, stream>>>(
        xn, wqkv, bqkv, nullptr, qkvb, MTOK, QKVN, CDIM);
    // 4) attention
    attn_kernel<<<dim3(16, NHEADS, BATCH), 256, 0, stream>>>(qkvb, ob);
    // 5) t = t + o @ wproj + bproj
    gemm_kernel<1, 0><<<dim3(CDIM / 64, MTOK / 64), 256, 0, stream>>>(
        ob, wproj, bproj, t, t, MTOK, CDIM, CDIM);
    // 6) LN2 (reuse xn buffer as yn)
    ln_kernel<<<dim3(MTOK), 128, 0, stream>>>(t, g2, b2, xn);
    // 7) h = gelu(yn @ w1 + bf1)   (h overwrites qkv+o region; both dead now)
    gemm_kernel<0, 1><<<dim3(FFN / 64, MTOK / 64), 256, 0, stream>>>(
        xn, w1, bf1, nullptr, hb, MTOK, FFN, CDIM);
    // 8) t = t + h @ w2 + bf2
    gemm_kernel<1, 0><<<dim3(CDIM / 64, MTOK / 64), 256, 0, stream>>>(
        hb, w2, bf2, t, t, MTOK, CDIM, FFN);
    // 9) transpose back to NCHW
    transpose_kernel<<<dim3(32, 12, BATCH), 256, 0, stream>>>(t, out);
}

// Round 2
// 511.834 us; speedup vs baseline: 3.5160x; 3.5160x over previous
//
#include <hip/hip_runtime.h>
#include <hip/hip_bf16.h>
#include <math.h>

#define BATCH 16
#define CDIM 384
#define HH 32
#define WW 32
#define NPIX 1024
#define MTOK (BATCH * NPIX)  // 16384
#define NHEADS 8
#define DH 48
#define QKVN (3 * CDIM)      // 1152
#define FFN (4 * CDIM)       // 1536

typedef unsigned short u16;
typedef __attribute__((ext_vector_type(8))) short short8;
typedef __attribute__((ext_vector_type(4))) float floatx4;

#define MFMA16(a, b, c) __builtin_amdgcn_mfma_f32_16x16x32_bf16(a, b, c, 0, 0, 0)

// ---------------------------------------------------------------------------
// depthwise 3x3 conv + identity + pos bias, written transposed to t[(b*N+p)*C+c]
// ---------------------------------------------------------------------------
__global__ void conv_pe_kernel(const float* __restrict__ x,
                               const float* __restrict__ pos_w,
                               const float* __restrict__ pos_b,
                               float* __restrict__ t) {
    int bc = blockIdx.x;
    int b = bc / CDIM, c = bc % CDIM;
    const float* xp = x + (size_t)bc * NPIX;
    float w[9];
#pragma unroll
    for (int i = 0; i < 9; ++i) w[i] = pos_w[c * 9 + i];
    float pb = pos_b[c];
    for (int p = threadIdx.x; p < NPIX; p += blockDim.x) {
        int h = p >> 5, wq = p & 31;
        float acc = 0.f;
#pragma unroll
        for (int kh = 0; kh < 3; ++kh) {
            int hh = h + kh - 1;
            if (hh < 0 || hh >= HH) continue;
#pragma unroll
            for (int kw = 0; kw < 3; ++kw) {
                int ww2 = wq + kw - 1;
                if (ww2 < 0 || ww2 >= WW) continue;
                acc += xp[hh * WW + ww2] * w[kh * 3 + kw];
            }
        }
        t[(size_t)(b * NPIX + p) * CDIM + c] = xp[p] + acc + pb;
    }
}

// ---------------------------------------------------------------------------
// row LayerNorm over C=384, bf16 output. 128 threads/row.
// ---------------------------------------------------------------------------
__global__ void ln_kernel(const float* __restrict__ in,
                          const float* __restrict__ g,
                          const float* __restrict__ bta,
                          __hip_bfloat16* __restrict__ out) {
    int m = blockIdx.x;
    const float* row = in + (size_t)m * CDIM;
    int tid = threadIdx.x;
    float v0 = row[tid], v1 = row[tid + 128], v2 = row[tid + 256];
    float s = v0 + v1 + v2;
    float ss = v0 * v0 + v1 * v1 + v2 * v2;
#pragma unroll
    for (int off = 32; off > 0; off >>= 1) {
        s += __shfl_down(s, off, 64);
        ss += __shfl_down(ss, off, 64);
    }
    __shared__ float red[4];
    if ((tid & 63) == 0) { red[tid >> 6] = s; red[2 + (tid >> 6)] = ss; }
    __syncthreads();
    float sum = red[0] + red[1], sumsq = red[2] + red[3];
    float mu = sum * (1.f / CDIM);
    float var = sumsq * (1.f / CDIM) - mu * mu;
    float rstd = rsqrtf(var + 1e-5f);
    __hip_bfloat16* orow = out + (size_t)m * CDIM;
    orow[tid]       = __float2bfloat16((v0 - mu) * rstd * g[tid] + bta[tid]);
    orow[tid + 128] = __float2bfloat16((v1 - mu) * rstd * g[tid + 128] + bta[tid + 128]);
    orow[tid + 256] = __float2bfloat16((v2 - mu) * rstd * g[tid + 256] + bta[tid + 256]);
}

// ---------------------------------------------------------------------------
// weight transpose+cast: Wt[n][k] = bf16(W[k][n]).  K,N multiples of 32.
// ---------------------------------------------------------------------------
__global__ void wt_kernel(const float* __restrict__ W, __hip_bfloat16* __restrict__ Wt,
                          int K, int N) {
    __shared__ float tile[32][33];
    int n0 = blockIdx.x * 32, k0 = blockIdx.y * 32;
    int tx = threadIdx.x & 31, ty = threadIdx.x >> 5;  // 256 threads
    for (int i = ty; i < 32; i += 8) tile[i][tx] = W[(size_t)(k0 + i) * N + n0 + tx];
    __syncthreads();
    for (int i = ty; i < 32; i += 8)
        Wt[(size_t)(n0 + i) * K + k0 + tx] = __float2bfloat16(tile[tx][i]);
}

// ---------------------------------------------------------------------------
// bf16 MFMA GEMM: C[M,N] = A[M,K] @ Bt[N,K]^T + bias (+Res) (+GELU)
// 128x128 tile, BK=32, 256 threads = 4 waves (2x2), each wave 64x64 (4x4 MFMA tiles)
// ---------------------------------------------------------------------------
template <int RES, int ACT, int OUTBF>
__global__ __launch_bounds__(256) void gemm_bf16(
    const u16* __restrict__ A, const u16* __restrict__ Bt,
    const float* __restrict__ bias, const float* __restrict__ Res,
    void* __restrict__ Cout, int N, int K) {
    __shared__ u16 As[128][32];
    __shared__ u16 Bs[128][32];
    const int tid = threadIdx.x;
    const int lane = tid & 63;
    const int wv = tid >> 6;
    const int qd = lane >> 4;
    const int l16 = lane & 15;
    const int wy = wv >> 1, wx = wv & 1;
    const int m0 = blockIdx.y * 128, n0 = blockIdx.x * 128;

    // staging: thread handles rows r0 and r0+64, 8 bf16 (16B) each
    const int r0 = tid >> 2, kc0 = (tid & 3) * 8;
    const u16* Ag = A + (size_t)(m0 + r0) * K + kc0;
    const u16* Bg = Bt + (size_t)(n0 + r0) * K + kc0;

    const floatx4 fz = {0.f, 0.f, 0.f, 0.f};
    floatx4 acc[4][4];
#pragma unroll
    for (int i = 0; i < 4; ++i)
#pragma unroll
        for (int j = 0; j < 4; ++j) acc[i][j] = fz;

    for (int k0 = 0; k0 < K; k0 += 32) {
        short8 a0 = *(const short8*)(Ag + k0);
        short8 a1 = *(const short8*)(Ag + (size_t)64 * K + k0);
        short8 b0 = *(const short8*)(Bg + k0);
        short8 b1 = *(const short8*)(Bg + (size_t)64 * K + k0);
        __syncthreads();
        *(short8*)&As[r0][kc0] = a0;
        *(short8*)&As[64 + r0][kc0] = a1;
        *(short8*)&Bs[r0][kc0] = b0;
        *(short8*)&Bs[64 + r0][kc0] = b1;
        __syncthreads();
        short8 af[4], bfr[4];
#pragma unroll
        for (int i = 0; i < 4; ++i) {
            af[i] = *(const short8*)&As[wy * 64 + i * 16 + l16][qd * 8];
            bfr[i] = *(const short8*)&Bs[wx * 64 + i * 16 + l16][qd * 8];
        }
#pragma unroll
        for (int i = 0; i < 4; ++i)
#pragma unroll
            for (int j = 0; j < 4; ++j) acc[i][j] = MFMA16(af[i], bfr[j], acc[i][j]);
    }

    // epilogue: lane holds D[row = qd*4+r][col = l16] per 16x16 tile
    const int colb = n0 + wx * 64 + l16;
    const int rowb = m0 + wy * 64 + qd * 4;
#pragma unroll
    for (int j = 0; j < 4; ++j) {
        int col = colb + j * 16;
        float bb = bias[col];
#pragma unroll
        for (int i = 0; i < 4; ++i) {
            int row = rowb + i * 16;
#pragma unroll
            for (int r = 0; r < 4; ++r) {
                float c = acc[i][j][r] + bb;
                if (RES) c += Res[(size_t)(row + r) * N + col];
                if (ACT) c = 0.5f * c * (1.f + erff(c * 0.70710678118654752f));
                if (OUTBF)
                    ((__hip_bfloat16*)Cout)[(size_t)(row + r) * N + col] = __float2bfloat16(c);
                else
                    ((float*)Cout)[(size_t)(row + r) * N + col] = c;
            }
        }
    }
}

// ---------------------------------------------------------------------------
// MFMA flash attention. Block = (qtile64, head, batch), 256 thr = 4 waves x 16 Q-rows.
// K zero-padded 48->64 in LDS; V transposed in LDS; P via per-wave LDS round-trip.
// ---------------------------------------------------------------------------
__global__ __launch_bounds__(256) void attn_kernel(const u16* __restrict__ qkv,
                                                   __hip_bfloat16* __restrict__ ob) {
    const int qb = blockIdx.x, h = blockIdx.y, b = blockIdx.z;
    const int tid = threadIdx.x;
    const int lane = tid & 63, wv = tid >> 6;
    const int qd = lane >> 4, l16 = lane & 15;

    __shared__ u16 Kl[64][72];                 // [key][k-dim padded 48->64, stride 72]
    __shared__ u16 Vt[48][72];                 // [dim][key], stride 72
    __shared__ __hip_bfloat16 Plds[4][16][40]; // per-wave P tile [qrow][32 keys]

    if (tid < 64) {
#pragma unroll
        for (int i = 0; i < 16; ++i) Kl[tid][48 + i] = 0;
    }

    const size_t bhbase = (size_t)(b * NPIX) * QKVN + h * DH;

    // Q fragments (A-operand: row = l16, k = qd*8+j), padded k 48->64 with zeros
    const u16* gq = qkv + bhbase + (size_t)(qb * 64 + wv * 16 + l16) * QKVN;
    short8 qf0 = *(const short8*)(gq + qd * 8);
    short8 qf1 = {0, 0, 0, 0, 0, 0, 0, 0};
    if (qd < 2) qf1 = *(const short8*)(gq + 32 + qd * 8);

    const floatx4 fz = {0.f, 0.f, 0.f, 0.f};
    floatx4 o[3] = {fz, fz, fz};
    float m_[4] = {-1e30f, -1e30f, -1e30f, -1e30f};
    float l_[4] = {0.f, 0.f, 0.f, 0.f};
    const float scale = 0.14433756729740643f;  // 1/sqrt(48)

    for (int kt = 0; kt < 16; ++kt) {  // 16 stages of 64 keys
        __syncthreads();
        const u16* kvbase = qkv + bhbase + (size_t)(kt * 64) * QKVN;
        // 768 copy tasks: 0..383 K chunks (16B), 384..767 V chunks (transpose)
#pragma unroll
        for (int tt = 0; tt < 3; ++tt) {
            int task = tid + tt * 256;
            if (task < 384) {
                int key = task / 6, ch = task % 6;
                short8 d = *(const short8*)(kvbase + (size_t)key * QKVN + CDIM + ch * 8);
                *(short8*)&Kl[key][ch * 8] = d;
            } else {
                int vt = task - 384;
                int key = vt / 6, ch = vt % 6;
                short8 d = *(const short8*)(kvbase + (size_t)key * QKVN + 2 * CDIM + ch * 8);
#pragma unroll
                for (int i = 0; i < 8; ++i) Vt[ch * 8 + i][key] = (u16)d[i];
            }
        }
        __syncthreads();

#pragma unroll
        for (int p = 0; p < 2; ++p) {  // 2 pairs of 16-key subtiles = 32 keys
            floatx4 sA = fz, sB = fz;
            short8 kb0 = *(const short8*)&Kl[p * 32 + l16][qd * 8];
            short8 kb1 = *(const short8*)&Kl[p * 32 + l16][32 + qd * 8];
            sA = MFMA16(qf0, kb0, sA);
            sA = MFMA16(qf1, kb1, sA);
            short8 kc0 = *(const short8*)&Kl[p * 32 + 16 + l16][qd * 8];
            short8 kc1 = *(const short8*)&Kl[p * 32 + 16 + l16][32 + qd * 8];
            sB = MFMA16(qf0, kc0, sB);
            sB = MFMA16(qf1, kc1, sB);

#pragma unroll
            for (int r = 0; r < 4; ++r) {
                float a_ = sA[r] * scale, b_ = sB[r] * scale;
                float mm = fmaxf(a_, b_);
                mm = fmaxf(mm, __shfl_xor(mm, 1, 64));
                mm = fmaxf(mm, __shfl_xor(mm, 2, 64));
                mm = fmaxf(mm, __shfl_xor(mm, 4, 64));
                mm = fmaxf(mm, __shfl_xor(mm, 8, 64));
                float mn = fmaxf(m_[r], mm);
                float alpha = __expf(m_[r] - mn);
                m_[r] = mn;
                float pA = __expf(a_ - mn), pB = __expf(b_ - mn);
                float rs = pA + pB;
                rs += __shfl_xor(rs, 1, 64);
                rs += __shfl_xor(rs, 2, 64);
                rs += __shfl_xor(rs, 4, 64);
                rs += __shfl_xor(rs, 8, 64);
                l_[r] = l_[r] * alpha + rs;
                Plds[wv][qd * 4 + r][l16] = __float2bfloat16(pA);
                Plds[wv][qd * 4 + r][16 + l16] = __float2bfloat16(pB);
                o[0][r] *= alpha;
                o[1][r] *= alpha;
                o[2][r] *= alpha;
            }
            // P back as A-operand (wave-internal LDS round-trip; waitcnt-ordered)
            short8 ap = *(const short8*)&Plds[wv][l16][qd * 8];
#pragma unroll
            for (int nt = 0; nt < 3; ++nt) {
                short8 bv = *(const short8*)&Vt[nt * 16 + l16][p * 32 + qd * 8];
                o[nt] = MFMA16(ap, bv, o[nt]);
            }
        }
    }

#pragma unroll
    for (int r = 0; r < 4; ++r) {
        float inv = 1.f / l_[r];
        size_t row = (size_t)(b * NPIX + qb * 64 + wv * 16 + qd * 4 + r) * CDIM + h * DH;
#pragma unroll
        for (int nt = 0; nt < 3; ++nt)
            ob[row + nt * 16 + l16] = __float2bfloat16(o[nt][r] * inv);
    }
}

// ---------------------------------------------------------------------------
// transpose (M,C) -> (B,C,H,W)
// ---------------------------------------------------------------------------
__global__ void transpose_kernel(const float* __restrict__ t, float* __restrict__ out) {
    __shared__ float tile[32][33];
    int b = blockIdx.z;
    int n0 = blockIdx.x * 32;
    int c0 = blockIdx.y * 32;
    int tx = threadIdx.x & 31;
    int ty = threadIdx.x >> 5;
    for (int i = ty; i < 32; i += 8)
        tile[i][tx] = t[(size_t)(b * NPIX + n0 + i) * CDIM + c0 + tx];
    __syncthreads();
    for (int i = ty; i < 32; i += 8)
        out[(size_t)(b * CDIM + c0 + i) * NPIX + n0 + tx] = tile[tx][i];
}

// ---------------------------------------------------------------------------
extern "C" void kernel_launch(void* const* d_in, const int* in_sizes, int n_in,
                              void* d_out, int out_size, void* d_ws, size_t ws_size,
                              hipStream_t stream) {
    const float* x = (const float*)d_in[0];
    const float* pos_w = (const float*)d_in[1];
    const float* pos_b = (const float*)d_in[2];
    const float* g1 = (const float*)d_in[3];
    const float* b1 = (const float*)d_in[4];
    const float* wqkv = (const float*)d_in[5];
    const float* bqkv = (const float*)d_in[6];
    const float* wproj = (const float*)d_in[7];
    const float* bproj = (const float*)d_in[8];
    const float* g2 = (const float*)d_in[9];
    const float* b2 = (const float*)d_in[10];
    const float* w1 = (const float*)d_in[11];
    const float* bf1 = (const float*)d_in[12];
    const float* w2 = (const float*)d_in[13];
    const float* bf2 = (const float*)d_in[14];
    float* out = (float*)d_out;

    // workspace layout (all offsets 16B-aligned)
    char* ws = (char*)d_ws;
    float* t = (float*)ws;                                        // 25165824 B
    __hip_bfloat16* xn = (__hip_bfloat16*)(ws + 25165824);        // 12582912 B
    __hip_bfloat16* wqkvT = (__hip_bfloat16*)(ws + 37748736);     // 884736 B
    __hip_bfloat16* wprojT = (__hip_bfloat16*)(ws + 38633472);    // 294912 B
    __hip_bfloat16* w1T = (__hip_bfloat16*)(ws + 38928384);       // 1179648 B
    __hip_bfloat16* w2T = (__hip_bfloat16*)(ws + 40108032);       // 1179648 B
    char* big = ws + 41287680;
    u16* qkvb = (u16*)big;                                        // 37748736 B
    __hip_bfloat16* obb = (__hip_bfloat16*)(big + 37748736);      // 12582912 B
    u16* hb = (u16*)big;                                          // 50331648 B (reuse)

    // weight prep (independent)
    wt_kernel<<<dim3(QKVN / 32, CDIM / 32), 256, 0, stream>>>(wqkv, wqkvT, CDIM, QKVN);
    wt_kernel<<<dim3(CDIM / 32, CDIM / 32), 256, 0, stream>>>(wproj, wprojT, CDIM, CDIM);
    wt_kernel<<<dim3(FFN / 32, CDIM / 32), 256, 0, stream>>>(w1, w1T, CDIM, FFN);
    wt_kernel<<<dim3(CDIM / 32, FFN / 32), 256, 0, stream>>>(w2, w2T, FFN, CDIM);

    conv_pe_kernel<<<dim3(BATCH * CDIM), 256, 0, stream>>>(x, pos_w, pos_b, t);
    ln_kernel<<<MTOK, 128, 0, stream>>>(t, g1, b1, xn);
    gemm_bf16<0, 0, 1><<<dim3(QKVN / 128, MTOK / 128), 256, 0, stream>>>(
        (const u16*)xn, (const u16*)wqkvT, bqkv, nullptr, qkvb, QKVN, CDIM);
    attn_kernel<<<dim3(16, NHEADS, BATCH), 256, 0, stream>>>(qkvb, obb);
    gemm_bf16<1, 0, 0><<<dim3(CDIM / 128, MTOK / 128), 256, 0, stream>>>(
        (const u16*)obb, (const u16*)wprojT, bproj, t, t, CDIM, CDIM);
    ln_kernel<<<MTOK, 128, 0, stream>>>(t, g2, b2, xn);
    gemm_bf16<0, 1, 1><<<dim3(FFN / 128, MTOK / 128), 256, 0, stream>>>(
        (const u16*)xn, (const u16*)w1T, bf1, nullptr, hb, FFN, CDIM);
    gemm_bf16<1, 0, 0><<<dim3(CDIM / 128, MTOK / 128), 256, 0, stream>>>(
        (const u16*)hb, (const u16*)w2T, bf2, t, t, CDIM, FFN);
    transpose_kernel<<<dim3(32, 12, BATCH), 256, 0, stream>>>(t, out);
}

// Round 3
// 489.122 us; speedup vs baseline: 3.6792x; 1.0464x over previous
//
#include <hip/hip_runtime.h>
#include <hip/hip_bf16.h>
#include <math.h>

#define BATCH 16
#define CDIM 384
#define HH 32
#define WW 32
#define NPIX 1024
#define MTOK (BATCH * NPIX)  // 16384
#define NHEADS 8
#define DH 48
#define QKVN (3 * CDIM)      // 1152
#define FFN (4 * CDIM)       // 1536

typedef unsigned short u16;
typedef unsigned int u32;
typedef __attribute__((ext_vector_type(8))) short short8;
typedef __attribute__((ext_vector_type(4))) float floatx4;

#define MFMA16(a, b, c) __builtin_amdgcn_mfma_f32_16x16x32_bf16(a, b, c, 0, 0, 0)

// async global->LDS 16B copy; LDS dest must be wave-uniform base + lane*16
__device__ __forceinline__ void gl2lds16(const void* g, void* l) {
    __builtin_amdgcn_global_load_lds(
        (const __attribute__((address_space(1))) void*)g,
        (__attribute__((address_space(3))) void*)l, 16, 0, 0);
}

// ---------------------------------------------------------------------------
// depthwise 3x3 conv + identity + pos bias, written transposed to t[(b*N+p)*C+c]
// ---------------------------------------------------------------------------
__global__ void conv_pe_kernel(const float* __restrict__ x,
                               const float* __restrict__ pos_w,
                               const float* __restrict__ pos_b,
                               float* __restrict__ t) {
    int bc = blockIdx.x;
    int b = bc / CDIM, c = bc % CDIM;
    const float* xp = x + (size_t)bc * NPIX;
    float w[9];
#pragma unroll
    for (int i = 0; i < 9; ++i) w[i] = pos_w[c * 9 + i];
    float pb = pos_b[c];
    for (int p = threadIdx.x; p < NPIX; p += blockDim.x) {
        int h = p >> 5, wq = p & 31;
        float acc = 0.f;
#pragma unroll
        for (int kh = 0; kh < 3; ++kh) {
            int hh = h + kh - 1;
            if (hh < 0 || hh >= HH) continue;
#pragma unroll
            for (int kw = 0; kw < 3; ++kw) {
                int ww2 = wq + kw - 1;
                if (ww2 < 0 || ww2 >= WW) continue;
                acc += xp[hh * WW + ww2] * w[kh * 3 + kw];
            }
        }
        t[(size_t)(b * NPIX + p) * CDIM + c] = xp[p] + acc + pb;
    }
}

// ---------------------------------------------------------------------------
// row LayerNorm over C=384, bf16 output. 128 threads/row.
// ---------------------------------------------------------------------------
__global__ void ln_kernel(const float* __restrict__ in,
                          const float* __restrict__ g,
                          const float* __restrict__ bta,
                          __hip_bfloat16* __restrict__ out) {
    int m = blockIdx.x;
    const float* row = in + (size_t)m * CDIM;
    int tid = threadIdx.x;
    float v0 = row[tid], v1 = row[tid + 128], v2 = row[tid + 256];
    float s = v0 + v1 + v2;
    float ss = v0 * v0 + v1 * v1 + v2 * v2;
#pragma unroll
    for (int off = 32; off > 0; off >>= 1) {
        s += __shfl_down(s, off, 64);
        ss += __shfl_down(ss, off, 64);
    }
    __shared__ float red[4];
    if ((tid & 63) == 0) { red[tid >> 6] = s; red[2 + (tid >> 6)] = ss; }
    __syncthreads();
    float sum = red[0] + red[1], sumsq = red[2] + red[3];
    float mu = sum * (1.f / CDIM);
    float var = sumsq * (1.f / CDIM) - mu * mu;
    float rstd = rsqrtf(var + 1e-5f);
    __hip_bfloat16* orow = out + (size_t)m * CDIM;
    orow[tid]       = __float2bfloat16((v0 - mu) * rstd * g[tid] + bta[tid]);
    orow[tid + 128] = __float2bfloat16((v1 - mu) * rstd * g[tid + 128] + bta[tid + 128]);
    orow[tid + 256] = __float2bfloat16((v2 - mu) * rstd * g[tid + 256] + bta[tid + 256]);
}

// ---------------------------------------------------------------------------
// weight transpose+cast: Wt[n][k] = bf16(W[k][n]).
// ---------------------------------------------------------------------------
__global__ void wt_kernel(const float* __restrict__ W, __hip_bfloat16* __restrict__ Wt,
                          int K, int N) {
    __shared__ float tile[32][33];
    int n0 = blockIdx.x * 32, k0 = blockIdx.y * 32;
    int tx = threadIdx.x & 31, ty = threadIdx.x >> 5;
    for (int i = ty; i < 32; i += 8) tile[i][tx] = W[(size_t)(k0 + i) * N + n0 + tx];
    __syncthreads();
    for (int i = ty; i < 32; i += 8)
        Wt[(size_t)(n0 + i) * K + k0 + tx] = __float2bfloat16(tile[tx][i]);
}

// ---------------------------------------------------------------------------
// V transpose: vT[(b*8+h)*48+d][key] = qkv[b][key][2C + h*48 + d]  (bf16)
// block = (key-tile 128, h, b); paid ONCE instead of per attention stage.
// ---------------------------------------------------------------------------
__global__ __launch_bounds__(256) void vtrans_kernel(const u16* __restrict__ qkv,
                                                     u16* __restrict__ vT) {
    __shared__ u16 Vl[48][136];  // stride 136 u16 = 272B (16B-mult); store-side reads conflict-free
    const int kt = blockIdx.x, h = blockIdx.y, b = blockIdx.z;
    const int tid = threadIdx.x;
    const size_t base = (size_t)b * NPIX * QKVN + 2 * CDIM + (size_t)h * DH;
#pragma unroll
    for (int it = 0; it < 3; ++it) {
        int task = tid + it * 256;          // 768 tasks: key 0..127, ch 0..5
        int key = task / 6, ch = task - key * 6;
        short8 v = *(const short8*)(qkv + base + (size_t)(kt * 128 + key) * QKVN + ch * 8);
#pragma unroll
        for (int i = 0; i < 8; ++i) Vl[ch * 8 + i][key] = (u16)v[i];
    }
    __syncthreads();
    u16* dst = vT + (size_t)(b * NHEADS + h) * DH * NPIX + (size_t)kt * 128;
#pragma unroll
    for (int it = 0; it < 3; ++it) {
        int task = tid + it * 256;          // 768 tasks: d 0..47, ch 0..15
        int d = task >> 4, ch = task & 15;
        short8 v = *(const short8*)&Vl[d][ch * 8];
        *(short8*)(dst + (size_t)d * NPIX + ch * 8) = v;   // coalesced 256B rows
    }
}

// ---------------------------------------------------------------------------
// bf16 MFMA GEMM: C[M,N] = A[M,K] @ Bt[N,K]^T + bias (+Res) (+GELU)
// 128x128 tile, BK=32, 4 waves (2x2), staging via global_load_lds dwordx4 (m97)
// ---------------------------------------------------------------------------
template <int RES, int ACT, int OUTBF>
__global__ __launch_bounds__(256) void gemm_bf16(
    const u16* __restrict__ A, const u16* __restrict__ Bt,
    const float* __restrict__ bias, const float* __restrict__ Res,
    void* __restrict__ Cout, int N, int K) {
    __shared__ u16 As[128][32];   // 64B rows; lane-contiguous for global_load_lds
    __shared__ u16 Bs[128][32];
    const int tid = threadIdx.x;
    const int lane = tid & 63;
    const int wv = tid >> 6;
    const int qd = lane >> 4;
    const int l16 = lane & 15;
    const int wy = wv >> 1, wx = wv & 1;
    const int m0 = blockIdx.y * 128, n0 = blockIdx.x * 128;

    const int r0 = tid >> 2, kc0 = (tid & 3) * 8;   // LDS offset = tid*16 bytes
    const u16* Ag = A + (size_t)(m0 + r0) * K + kc0;
    const u16* Bg = Bt + (size_t)(n0 + r0) * K + kc0;
    u16* AsL0 = &As[0][0] + tid * 8;
    u16* AsL1 = &As[0][0] + 2048 + tid * 8;
    u16* BsL0 = &Bs[0][0] + tid * 8;
    u16* BsL1 = &Bs[0][0] + 2048 + tid * 8;

    const floatx4 fz = {0.f, 0.f, 0.f, 0.f};
    floatx4 acc[4][4];
#pragma unroll
    for (int i = 0; i < 4; ++i)
#pragma unroll
        for (int j = 0; j < 4; ++j) acc[i][j] = fz;

    for (int k0 = 0; k0 < K; k0 += 32) {
        __syncthreads();
        gl2lds16(Ag + k0, AsL0);
        gl2lds16(Ag + (size_t)64 * K + k0, AsL1);
        gl2lds16(Bg + k0, BsL0);
        gl2lds16(Bg + (size_t)64 * K + k0, BsL1);
        __syncthreads();   // drains vmcnt -> LDS visible
        short8 af[4], bfr[4];
#pragma unroll
        for (int i = 0; i < 4; ++i) {
            af[i] = *(const short8*)&As[wy * 64 + i * 16 + l16][qd * 8];
            bfr[i] = *(const short8*)&Bs[wx * 64 + i * 16 + l16][qd * 8];
        }
#pragma unroll
        for (int i = 0; i < 4; ++i)
#pragma unroll
            for (int j = 0; j < 4; ++j) acc[i][j] = MFMA16(af[i], bfr[j], acc[i][j]);
    }

    const int colb = n0 + wx * 64 + l16;
    const int rowb = m0 + wy * 64 + qd * 4;
#pragma unroll
    for (int j = 0; j < 4; ++j) {
        int col = colb + j * 16;
        float bb = bias[col];
#pragma unroll
        for (int i = 0; i < 4; ++i) {
            int row = rowb + i * 16;
#pragma unroll
            for (int r = 0; r < 4; ++r) {
                float c = acc[i][j][r] + bb;
                if (RES) c += Res[(size_t)(row + r) * N + col];
                if (ACT) c = 0.5f * c * (1.f + erff(c * 0.70710678118654752f));
                if (OUTBF)
                    ((__hip_bfloat16*)Cout)[(size_t)(row + r) * N + col] = __float2bfloat16(c);
                else
                    ((float*)Cout)[(size_t)(row + r) * N + col] = c;
            }
        }
    }
}

// ---------------------------------------------------------------------------
// MFMA flash attention. Block = (qtile128, h, b); 4 waves x 32 queries.
// K staged async (unpadded 96B rows, lane-contiguous); V from pre-transposed vT.
// One softmax reduction round per 64-key stage. All LDS b128 ops conflict-free.
// ---------------------------------------------------------------------------
__global__ __launch_bounds__(256) void attn_kernel(const u16* __restrict__ qkv,
                                                   const u16* __restrict__ vT,
                                                   __hip_bfloat16* __restrict__ ob) {
    const int qb = blockIdx.x, h = blockIdx.y, b = blockIdx.z;
    const int tid = threadIdx.x;
    const int lane = tid & 63, wv = tid >> 6;
    const int qd = lane >> 4, l16 = lane & 15;

    __shared__ u16 Kl[65][48];               // [key][d], +1 zero safety row
    __shared__ u16 Vt[48][72];               // [d][key], stride 72
    __shared__ __hip_bfloat16 Pl[4][32][72]; // per-wave P [qrow 32][key 64], stride 72

    if (tid < 24) ((u32*)&Kl[64][0])[tid] = 0;  // zero safety row (hi-frag overread)

    const size_t bh = (size_t)b * NPIX * QKVN + (size_t)h * DH;
    const u16* vtb = vT + (size_t)(b * NHEADS + h) * DH * NPIX;

    // Q fragments: wave covers queries qb*128 + wv*32 + g*16 + l16; k padded 48->64
    short8 qf[2][2];
    const short8 z8 = {0, 0, 0, 0, 0, 0, 0, 0};
#pragma unroll
    for (int g = 0; g < 2; ++g) {
        const u16* gq = qkv + bh + (size_t)(qb * 128 + wv * 32 + g * 16 + l16) * QKVN;
        qf[g][0] = *(const short8*)(gq + qd * 8);
        qf[g][1] = (qd < 2) ? *(const short8*)(gq + 32 + qd * 8) : z8;
    }

    const floatx4 fz = {0.f, 0.f, 0.f, 0.f};
    floatx4 o[2][3];
    float m_[2][4], l_[2][4];
#pragma unroll
    for (int g = 0; g < 2; ++g) {
#pragma unroll
        for (int nt = 0; nt < 3; ++nt) o[g][nt] = fz;
#pragma unroll
        for (int r = 0; r < 4; ++r) { m_[g][r] = -1e30f; l_[g][r] = 0.f; }
    }
    const float scale = 0.14433756729740643f;  // 1/sqrt(48)

    for (int kt = 0; kt < 16; ++kt) {
        __syncthreads();
        {
            const size_t kbase = bh + (size_t)(kt * 64) * QKVN + CDIM;
            int key = tid / 6, ch = tid - key * 6;  // 384 chunks, lane-linear LDS
            gl2lds16(qkv + kbase + (size_t)key * QKVN + ch * 8, &Kl[0][0] + tid * 8);
            if (tid < 128) {
                int t2 = tid + 256;
                int k2 = t2 / 6, c2 = t2 - k2 * 6;
                gl2lds16(qkv + kbase + (size_t)k2 * QKVN + c2 * 8, &Kl[0][0] + t2 * 8);
            }
            int d = tid >> 3, vc = tid & 7;         // 384 V chunks (b128 round-trip)
            short8 v0 = *(const short8*)(vtb + (size_t)d * NPIX + kt * 64 + vc * 8);
            *(short8*)&Vt[d][vc * 8] = v0;
            if (tid < 128) {
                int d1 = (tid + 256) >> 3;
                short8 v1 = *(const short8*)(vtb + (size_t)d1 * NPIX + kt * 64 + vc * 8);
                *(short8*)&Vt[d1][vc * 8] = v1;
            }
        }
        __syncthreads();

        // QK^T: K frags loaded once, reused for both Q sub-tiles
        short8 kl[4], kh[4];
#pragma unroll
        for (int t = 0; t < 4; ++t) {
            const u16* kr = &Kl[0][0] + (t * 16 + l16) * 48;
            kl[t] = *(const short8*)(kr + qd * 8);
            kh[t] = *(const short8*)(kr + 32 + qd * 8);  // cols 48..63 hit zeros/next-row; qf[g][1]=0 there
        }
        floatx4 s[2][4];
#pragma unroll
        for (int g = 0; g < 2; ++g)
#pragma unroll
            for (int t = 0; t < 4; ++t) {
                floatx4 a = fz;
                a = MFMA16(qf[g][0], kl[t], a);
                a = MFMA16(qf[g][1], kh[t], a);
                s[g][t] = a;
            }

        // online softmax: one reduction round over all 64 keys
#pragma unroll
        for (int g = 0; g < 2; ++g)
#pragma unroll
            for (int r = 0; r < 4; ++r) {
                float v0 = s[g][0][r] * scale, v1 = s[g][1][r] * scale;
                float v2 = s[g][2][r] * scale, v3 = s[g][3][r] * scale;
                float mloc = fmaxf(fmaxf(v0, v1), fmaxf(v2, v3));
                mloc = fmaxf(mloc, __shfl_xor(mloc, 1, 64));
                mloc = fmaxf(mloc, __shfl_xor(mloc, 2, 64));
                mloc = fmaxf(mloc, __shfl_xor(mloc, 4, 64));
                mloc = fmaxf(mloc, __shfl_xor(mloc, 8, 64));
                float mn = fmaxf(m_[g][r], mloc);
                float alpha = __expf(m_[g][r] - mn);
                m_[g][r] = mn;
                float p0 = __expf(v0 - mn), p1 = __expf(v1 - mn);
                float p2 = __expf(v2 - mn), p3 = __expf(v3 - mn);
                float rs = (p0 + p1) + (p2 + p3);
                rs += __shfl_xor(rs, 1, 64);
                rs += __shfl_xor(rs, 2, 64);
                rs += __shfl_xor(rs, 4, 64);
                rs += __shfl_xor(rs, 8, 64);
                l_[g][r] = l_[g][r] * alpha + rs;
                o[g][0][r] *= alpha;
                o[g][1][r] *= alpha;
                o[g][2][r] *= alpha;
                __hip_bfloat16* pr = &Pl[wv][g * 16 + qd * 4 + r][0];
                pr[l16] = __float2bfloat16(p0);
                pr[16 + l16] = __float2bfloat16(p1);
                pr[32 + l16] = __float2bfloat16(p2);
                pr[48 + l16] = __float2bfloat16(p3);
            }

        // PV: V frags loaded once, reused for both Q sub-tiles (same-wave LDS RAW)
        short8 vl[3], vh[3];
#pragma unroll
        for (int nt = 0; nt < 3; ++nt) {
            const u16* vr = &Vt[0][0] + (nt * 16 + l16) * 72;
            vl[nt] = *(const short8*)(vr + qd * 8);
            vh[nt] = *(const short8*)(vr + 32 + qd * 8);
        }
#pragma unroll
        for (int g = 0; g < 2; ++g) {
            const __hip_bfloat16* prr = &Pl[wv][g * 16 + l16][0];
            short8 ap0 = *(const short8*)(prr + qd * 8);
            short8 ap1 = *(const short8*)(prr + 32 + qd * 8);
#pragma unroll
            for (int nt = 0; nt < 3; ++nt) {
                o[g][nt] = MFMA16(ap0, vl[nt], o[g][nt]);
                o[g][nt] = MFMA16(ap1, vh[nt], o[g][nt]);
            }
        }
    }

#pragma unroll
    for (int g = 0; g < 2; ++g)
#pragma unroll
        for (int r = 0; r < 4; ++r) {
            float inv = 1.f / l_[g][r];
            size_t row = (size_t)(b * NPIX + qb * 128 + wv * 32 + g * 16 + qd * 4 + r) * CDIM + h * DH;
#pragma unroll
            for (int nt = 0; nt < 3; ++nt)
                ob[row + nt * 16 + l16] = __float2bfloat16(o[g][nt][r] * inv);
        }
}

// ---------------------------------------------------------------------------
// transpose (M,C) -> (B,C,H,W)
// ---------------------------------------------------------------------------
__global__ void transpose_kernel(const float* __restrict__ t, float* __restrict__ out) {
    __shared__ float tile[32][33];
    int b = blockIdx.z;
    int n0 = blockIdx.x * 32;
    int c0 = blockIdx.y * 32;
    int tx = threadIdx.x & 31;
    int ty = threadIdx.x >> 5;
    for (int i = ty; i < 32; i += 8)
        tile[i][tx] = t[(size_t)(b * NPIX + n0 + i) * CDIM + c0 + tx];
    __syncthreads();
    for (int i = ty; i < 32; i += 8)
        out[(size_t)(b * CDIM + c0 + i) * NPIX + n0 + tx] = tile[tx][i];
}

// ---------------------------------------------------------------------------
extern "C" void kernel_launch(void* const* d_in, const int* in_sizes, int n_in,
                              void* d_out, int out_size, void* d_ws, size_t ws_size,
                              hipStream_t stream) {
    const float* x = (const float*)d_in[0];
    const float* pos_w = (const float*)d_in[1];
    const float* pos_b = (const float*)d_in[2];
    const float* g1 = (const float*)d_in[3];
    const float* b1 = (const float*)d_in[4];
    const float* wqkv = (const float*)d_in[5];
    const float* bqkv = (const float*)d_in[6];
    const float* wproj = (const float*)d_in[7];
    const float* bproj = (const float*)d_in[8];
    const float* g2 = (const float*)d_in[9];
    const float* b2 = (const float*)d_in[10];
    const float* w1 = (const float*)d_in[11];
    const float* bf1 = (const float*)d_in[12];
    const float* w2 = (const float*)d_in[13];
    const float* bf2 = (const float*)d_in[14];
    float* out = (float*)d_out;

    // workspace layout (16B-aligned); total 91.6 MB (same as round 2)
    char* ws = (char*)d_ws;
    float* t = (float*)ws;                                        // 25165824 B
    __hip_bfloat16* xn = (__hip_bfloat16*)(ws + 25165824);        // 12582912 B
    u16* vTb = (u16*)xn;  // vT reuses xn: xn dead after qkv GEMM, vT dead before LN2
    __hip_bfloat16* wqkvT = (__hip_bfloat16*)(ws + 37748736);
    __hip_bfloat16* wprojT = (__hip_bfloat16*)(ws + 38633472);
    __hip_bfloat16* w1T = (__hip_bfloat16*)(ws + 38928384);
    __hip_bfloat16* w2T = (__hip_bfloat16*)(ws + 40108032);
    char* big = ws + 41287680;
    u16* qkvb = (u16*)big;                                        // 37748736 B
    __hip_bfloat16* obb = (__hip_bfloat16*)(big + 37748736);      // 12582912 B
    u16* hb = (u16*)big;                                          // 50331648 B (reuse)

    wt_kernel<<<dim3(QKVN / 32, CDIM / 32), 256, 0, stream>>>(wqkv, wqkvT, CDIM, QKVN);
    wt_kernel<<<dim3(CDIM / 32, CDIM / 32), 256, 0, stream>>>(wproj, wprojT, CDIM, CDIM);
    wt_kernel<<<dim3(FFN / 32, CDIM / 32), 256, 0, stream>>>(w1, w1T, CDIM, FFN);
    wt_kernel<<<dim3(CDIM / 32, FFN / 32), 256, 0, stream>>>(w2, w2T, FFN, CDIM);

    conv_pe_kernel<<<dim3(BATCH * CDIM), 256, 0, stream>>>(x, pos_w, pos_b, t);
    ln_kernel<<<MTOK, 128, 0, stream>>>(t, g1, b1, xn);
    gemm_bf16<0, 0, 1><<<dim3(QKVN / 128, MTOK / 128), 256, 0, stream>>>(
        (const u16*)xn, (const u16*)wqkvT, bqkv, nullptr, qkvb, QKVN, CDIM);
    vtrans_kernel<<<dim3(NPIX / 128, NHEADS, BATCH), 256, 0, stream>>>(qkvb, vTb);
    attn_kernel<<<dim3(NPIX / 128, NHEADS, BATCH), 256, 0, stream>>>(qkvb, vTb, obb);
    gemm_bf16<1, 0, 0><<<dim3(CDIM / 128, MTOK / 128), 256, 0, stream>>>(
        (const u16*)obb, (const u16*)wprojT, bproj, t, t, CDIM, CDIM);
    ln_kernel<<<MTOK, 128, 0, stream>>>(t, g2, b2, xn);
    gemm_bf16<0, 1, 1><<<dim3(FFN / 128, MTOK / 128), 256, 0, stream>>>(
        (const u16*)xn, (const u16*)w1T, bf1, nullptr, hb, FFN, CDIM);
    gemm_bf16<1, 0, 0><<<dim3(CDIM / 128, MTOK / 128), 256, 0, stream>>>(
        (const u16*)hb, (const u16*)w2T, bf2, t, t, CDIM, FFN);
    transpose_kernel<<<dim3(32, 12, BATCH), 256, 0, stream>>>(t, out);
}

// Round 4
// 378.761 us; speedup vs baseline: 4.7513x; 1.2914x over previous
//
#include <hip/hip_runtime.h>
#include <hip/hip_bf16.h>
#include <math.h>

#define BATCH 16
#define CDIM 384
#define HH 32
#define WW 32
#define NPIX 1024
#define MTOK (BATCH * NPIX)  // 16384
#define NHEADS 8
#define DH 48
#define QKVN (3 * CDIM)      // 1152
#define FFN (4 * CDIM)       // 1536

typedef unsigned short u16;
typedef unsigned int u32;
typedef __attribute__((ext_vector_type(8))) short short8;
typedef __attribute__((ext_vector_type(4))) float floatx4;

#define MFMA16(a, b, c) __builtin_amdgcn_mfma_f32_16x16x32_bf16(a, b, c, 0, 0, 0)

// async global->LDS 16B copy; LDS dest must be wave-uniform base + lane*16
__device__ __forceinline__ void gl2lds16(const void* g, void* l) {
    __builtin_amdgcn_global_load_lds(
        (const __attribute__((address_space(1))) void*)g,
        (__attribute__((address_space(3))) void*)l, 16, 0, 0);
}

// ---------------------------------------------------------------------------
// depthwise 3x3 conv + identity + pos bias -> t[(b*N+p)*C+c], coalesced writes.
// block = (ch-group 64, image row h, b); 256 threads.
// ---------------------------------------------------------------------------
__global__ __launch_bounds__(256) void conv_pe_kernel(const float* __restrict__ x,
                                                      const float* __restrict__ pos_w,
                                                      const float* __restrict__ pos_b,
                                                      float* __restrict__ t) {
    __shared__ float xs[64][100];  // [c][row*32+w], stride 100 (16B-mult, 2-way max)
    __shared__ float os[32][68];   // [w][c], stride 68 (16B-mult)
    const int cg = blockIdx.x, h = blockIdx.y, b = blockIdx.z;
    const int tid = threadIdx.x;
    const int c0 = cg * 64;

    // load 64ch x 3 rows x 32w as float4 (zero halo rows at image edge)
#pragma unroll
    for (int it = 0; it < 6; ++it) {
        int task = tid + it * 256;            // 1536 tasks
        int c = task / 24, rem = task % 24;
        int row = rem >> 3, f4 = rem & 7;
        int hh = h + row - 1;
        float4 v = {0.f, 0.f, 0.f, 0.f};
        if (hh >= 0 && hh < HH)
            v = *(const float4*)(x + (((size_t)(b * CDIM + c0 + c) * HH + hh) * WW + f4 * 4));
        *(float4*)&xs[c][row * 32 + f4 * 4] = v;
    }
    __syncthreads();

    const int c = tid >> 2, w0 = (tid & 3) * 8;
    float wgt[9];
#pragma unroll
    for (int i = 0; i < 9; ++i) wgt[i] = pos_w[(c0 + c) * 9 + i];
    const float pb = pos_b[c0 + c];
#pragma unroll
    for (int wi = 0; wi < 8; ++wi) {
        int w = w0 + wi;
        float acc = 0.f;
#pragma unroll
        for (int r = 0; r < 3; ++r)
#pragma unroll
            for (int kw = 0; kw < 3; ++kw) {
                int w2 = w + kw - 1;
                if (w2 >= 0 && w2 < WW) acc += xs[c][r * 32 + w2] * wgt[r * 3 + kw];
            }
        os[w][c] = xs[c][32 + w] + acc + pb;
    }
    __syncthreads();

    float* dstb = t + (size_t)(b * NPIX + h * 32) * CDIM + c0;
#pragma unroll
    for (int it = 0; it < 2; ++it) {
        int task = tid + it * 256;            // 512 tasks: px 0..31, f4 0..15
        int px = task >> 4, f4 = task & 15;
        *(float4*)(dstb + (size_t)px * CDIM + f4 * 4) = *(const float4*)&os[px][f4 * 4];
    }
}

// ---------------------------------------------------------------------------
// row LayerNorm over C=384, bf16 output. 128 threads/row.
// ---------------------------------------------------------------------------
__global__ void ln_kernel(const float* __restrict__ in,
                          const float* __restrict__ g,
                          const float* __restrict__ bta,
                          __hip_bfloat16* __restrict__ out) {
    int m = blockIdx.x;
    const float* row = in + (size_t)m * CDIM;
    int tid = threadIdx.x;
    float v0 = row[tid], v1 = row[tid + 128], v2 = row[tid + 256];
    float s = v0 + v1 + v2;
    float ss = v0 * v0 + v1 * v1 + v2 * v2;
#pragma unroll
    for (int off = 32; off > 0; off >>= 1) {
        s += __shfl_down(s, off, 64);
        ss += __shfl_down(ss, off, 64);
    }
    __shared__ float red[4];
    if ((tid & 63) == 0) { red[tid >> 6] = s; red[2 + (tid >> 6)] = ss; }
    __syncthreads();
    float sum = red[0] + red[1], sumsq = red[2] + red[3];
    float mu = sum * (1.f / CDIM);
    float var = sumsq * (1.f / CDIM) - mu * mu;
    float rstd = rsqrtf(var + 1e-5f);
    __hip_bfloat16* orow = out + (size_t)m * CDIM;
    orow[tid]       = __float2bfloat16((v0 - mu) * rstd * g[tid] + bta[tid]);
    orow[tid + 128] = __float2bfloat16((v1 - mu) * rstd * g[tid + 128] + bta[tid + 128]);
    orow[tid + 256] = __float2bfloat16((v2 - mu) * rstd * g[tid + 256] + bta[tid + 256]);
}

// ---------------------------------------------------------------------------
// weight transpose+cast: Wt[n][k] = bf16(W[k][n]).
// ---------------------------------------------------------------------------
__global__ void wt_kernel(const float* __restrict__ W, __hip_bfloat16* __restrict__ Wt,
                          int K, int N) {
    __shared__ float tile[32][33];
    int n0 = blockIdx.x * 32, k0 = blockIdx.y * 32;
    int tx = threadIdx.x & 31, ty = threadIdx.x >> 5;
    for (int i = ty; i < 32; i += 8) tile[i][tx] = W[(size_t)(k0 + i) * N + n0 + tx];
    __syncthreads();
    for (int i = ty; i < 32; i += 8)
        Wt[(size_t)(n0 + i) * K + k0 + tx] = __float2bfloat16(tile[tx][i]);
}

// ---------------------------------------------------------------------------
// V transpose: vT[(b*8+h)*48+d][key] = qkv[b][key][2C + h*48 + d]  (bf16)
// ---------------------------------------------------------------------------
__global__ __launch_bounds__(256) void vtrans_kernel(const u16* __restrict__ qkv,
                                                     u16* __restrict__ vT) {
    __shared__ u16 Vl[48][136];
    const int kt = blockIdx.x, h = blockIdx.y, b = blockIdx.z;
    const int tid = threadIdx.x;
    const size_t base = (size_t)b * NPIX * QKVN + 2 * CDIM + (size_t)h * DH;
#pragma unroll
    for (int it = 0; it < 3; ++it) {
        int task = tid + it * 256;
        int key = task / 6, ch = task - key * 6;
        short8 v = *(const short8*)(qkv + base + (size_t)(kt * 128 + key) * QKVN + ch * 8);
#pragma unroll
        for (int i = 0; i < 8; ++i) Vl[ch * 8 + i][key] = (u16)v[i];
    }
    __syncthreads();
    u16* dst = vT + (size_t)(b * NHEADS + h) * DH * NPIX + (size_t)kt * 128;
#pragma unroll
    for (int it = 0; it < 3; ++it) {
        int task = tid + it * 256;
        int d = task >> 4, ch = task & 15;
        short8 v = *(const short8*)&Vl[d][ch * 8];
        *(short8*)(dst + (size_t)d * NPIX + ch * 8) = v;
    }
}

// ---------------------------------------------------------------------------
// bf16 MFMA GEMM: C[M,N] = A[M,K] @ Bt[N,K]^T + bias (+Res) (+GELU)
// BM=128, BN in {128,64}; 4 waves (2x2); global_load_lds staging.
// ---------------------------------------------------------------------------
template <int BN, int RES, int ACT, int OUTBF>
__global__ __launch_bounds__(256) void gemm_bf16(
    const u16* __restrict__ A, const u16* __restrict__ Bt,
    const float* __restrict__ bias, const float* __restrict__ Res,
    void* __restrict__ Cout, int N, int K) {
    __shared__ u16 As[128][32];
    __shared__ u16 Bs[BN][32];
    constexpr int NF = BN / 32;  // b-frags per wave
    const int tid = threadIdx.x;
    const int lane = tid & 63;
    const int wv = tid >> 6;
    const int qd = lane >> 4;
    const int l16 = lane & 15;
    const int wy = wv >> 1, wx = wv & 1;
    const int m0 = blockIdx.y * 128, n0 = blockIdx.x * BN;

    const int r0 = tid >> 2, kc0 = (tid & 3) * 8;
    const u16* Ag = A + (size_t)(m0 + r0) * K + kc0;
    const u16* Bg = Bt + (size_t)(n0 + (BN == 64 ? (r0 & 63) : r0)) * K + kc0;
    u16* AsL0 = &As[0][0] + tid * 8;
    u16* AsL1 = &As[0][0] + 2048 + tid * 8;
    u16* BsL0 = &Bs[0][0] + tid * 8;
    u16* BsL1 = &Bs[0][0] + 2048 + tid * 8;  // only used when BN==128

    const floatx4 fz = {0.f, 0.f, 0.f, 0.f};
    floatx4 acc[4][NF];
#pragma unroll
    for (int i = 0; i < 4; ++i)
#pragma unroll
        for (int j = 0; j < NF; ++j) acc[i][j] = fz;

    for (int k0 = 0; k0 < K; k0 += 32) {
        __syncthreads();
        gl2lds16(Ag + k0, AsL0);
        gl2lds16(Ag + (size_t)64 * K + k0, AsL1);
        gl2lds16(Bg + k0, BsL0);
        if (BN == 128) gl2lds16(Bg + (size_t)64 * K + k0, BsL1);
        __syncthreads();
        short8 af[4], bfr[NF];
#pragma unroll
        for (int i = 0; i < 4; ++i)
            af[i] = *(const short8*)&As[wy * 64 + i * 16 + l16][qd * 8];
#pragma unroll
        for (int j = 0; j < NF; ++j)
            bfr[j] = *(const short8*)&Bs[wx * (BN / 2) + j * 16 + l16][qd * 8];
#pragma unroll
        for (int i = 0; i < 4; ++i)
#pragma unroll
            for (int j = 0; j < NF; ++j) acc[i][j] = MFMA16(af[i], bfr[j], acc[i][j]);
    }

    const int colb = n0 + wx * (BN / 2) + l16;
    const int rowb = m0 + wy * 64 + qd * 4;
#pragma unroll
    for (int j = 0; j < NF; ++j) {
        int col = colb + j * 16;
        float bb = bias[col];
#pragma unroll
        for (int i = 0; i < 4; ++i) {
            int row = rowb + i * 16;
#pragma unroll
            for (int r = 0; r < 4; ++r) {
                float c = acc[i][j][r] + bb;
                if (RES) c += Res[(size_t)(row + r) * N + col];
                if (ACT) c = 0.5f * c * (1.f + erff(c * 0.70710678118654752f));
                if (OUTBF)
                    ((__hip_bfloat16*)Cout)[(size_t)(row + r) * N + col] = __float2bfloat16(c);
                else
                    ((float*)Cout)[(size_t)(row + r) * N + col] = c;
            }
        }
    }
}

// ---------------------------------------------------------------------------
// MFMA flash attention, no-running-max softmax (scores provably tiny), deferred
// normalization. Linear grid with h-major decode -> same-head blocks share XCD.
// ---------------------------------------------------------------------------
__global__ __launch_bounds__(256) void attn_kernel(const u16* __restrict__ qkv,
                                                   const u16* __restrict__ vT,
                                                   __hip_bfloat16* __restrict__ ob) {
    const int id = blockIdx.x;
    const int h = id & 7;
    const int b = (id >> 3) & 15;
    const int qb = id >> 7;  // 0..7
    const int tid = threadIdx.x;
    const int lane = tid & 63, wv = tid >> 6;
    const int qd = lane >> 4, l16 = lane & 15;

    __shared__ u16 Kl[65][48];               // [key][d], +1 zero safety row
    __shared__ u16 Vt[48][72];               // [d][key]
    __shared__ __hip_bfloat16 Pl[4][32][72]; // per-wave P [qrow 32][key 64]

    if (tid < 24) ((u32*)&Kl[64][0])[tid] = 0;

    const size_t bh = (size_t)b * NPIX * QKVN + (size_t)h * DH;
    const u16* vtb = vT + (size_t)(b * NHEADS + h) * DH * NPIX;

    short8 qf[2][2];
    const short8 z8 = {0, 0, 0, 0, 0, 0, 0, 0};
#pragma unroll
    for (int g = 0; g < 2; ++g) {
        const u16* gq = qkv + bh + (size_t)(qb * 128 + wv * 32 + g * 16 + l16) * QKVN;
        qf[g][0] = *(const short8*)(gq + qd * 8);
        qf[g][1] = (qd < 2) ? *(const short8*)(gq + 32 + qd * 8) : z8;
    }

    const floatx4 fz = {0.f, 0.f, 0.f, 0.f};
    floatx4 o[2][3];
    float lsum[2][4];
#pragma unroll
    for (int g = 0; g < 2; ++g) {
#pragma unroll
        for (int nt = 0; nt < 3; ++nt) o[g][nt] = fz;
#pragma unroll
        for (int r = 0; r < 4; ++r) lsum[g][r] = 0.f;
    }
    const float scale = 0.14433756729740643f;  // 1/sqrt(48)

    for (int kt = 0; kt < 16; ++kt) {
        __syncthreads();
        {
            const size_t kbase = bh + (size_t)(kt * 64) * QKVN + CDIM;
            int key = tid / 6, ch = tid - key * 6;
            gl2lds16(qkv + kbase + (size_t)key * QKVN + ch * 8, &Kl[0][0] + tid * 8);
            if (tid < 128) {
                int t2 = tid + 256;
                int k2 = t2 / 6, c2 = t2 - k2 * 6;
                gl2lds16(qkv + kbase + (size_t)k2 * QKVN + c2 * 8, &Kl[0][0] + t2 * 8);
            }
            int d = tid >> 3, vc = tid & 7;
            short8 v0 = *(const short8*)(vtb + (size_t)d * NPIX + kt * 64 + vc * 8);
            *(short8*)&Vt[d][vc * 8] = v0;
            if (tid < 128) {
                int d1 = (tid + 256) >> 3;
                short8 v1 = *(const short8*)(vtb + (size_t)d1 * NPIX + kt * 64 + vc * 8);
                *(short8*)&Vt[d1][vc * 8] = v1;
            }
        }
        __syncthreads();

        // QK^T
        short8 kl[4], kh[4];
#pragma unroll
        for (int t = 0; t < 4; ++t) {
            const u16* kr = &Kl[0][0] + (t * 16 + l16) * 48;
            kl[t] = *(const short8*)(kr + qd * 8);
            kh[t] = *(const short8*)(kr + 32 + qd * 8);
        }
        floatx4 s[2][4];
#pragma unroll
        for (int g = 0; g < 2; ++g)
#pragma unroll
            for (int t = 0; t < 4; ++t) {
                floatx4 a = fz;
                a = MFMA16(qf[g][0], kl[t], a);
                a = MFMA16(qf[g][1], kh[t], a);
                s[g][t] = a;
            }

        // p = exp(s*scale); store P; accumulate per-lane partial sums (no reductions!)
#pragma unroll
        for (int g = 0; g < 2; ++g)
#pragma unroll
            for (int t = 0; t < 4; ++t) {
#pragma unroll
                for (int r = 0; r < 4; ++r) {
                    float p = __expf(s[g][t][r] * scale);
                    Pl[wv][g * 16 + qd * 4 + r][t * 16 + l16] = __float2bfloat16(p);
                    lsum[g][r] += p;
                }
            }

        // PV
        short8 vl[3], vh[3];
#pragma unroll
        for (int nt = 0; nt < 3; ++nt) {
            const u16* vr = &Vt[0][0] + (nt * 16 + l16) * 72;
            vl[nt] = *(const short8*)(vr + qd * 8);
            vh[nt] = *(const short8*)(vr + 32 + qd * 8);
        }
#pragma unroll
        for (int g = 0; g < 2; ++g) {
            const __hip_bfloat16* prr = &Pl[wv][g * 16 + l16][0];
            short8 ap0 = *(const short8*)(prr + qd * 8);
            short8 ap1 = *(const short8*)(prr + 32 + qd * 8);
#pragma unroll
            for (int nt = 0; nt < 3; ++nt) {
                o[g][nt] = MFMA16(ap0, vl[nt], o[g][nt]);
                o[g][nt] = MFMA16(ap1, vh[nt], o[g][nt]);
            }
        }
    }

    // one reduction at the end: row-sum across the 16 l16 lanes
#pragma unroll
    for (int g = 0; g < 2; ++g)
#pragma unroll
        for (int r = 0; r < 4; ++r) {
            float l = lsum[g][r];
            l += __shfl_xor(l, 1, 64);
            l += __shfl_xor(l, 2, 64);
            l += __shfl_xor(l, 4, 64);
            l += __shfl_xor(l, 8, 64);
            float inv = 1.f / l;
            size_t row = (size_t)(b * NPIX + qb * 128 + wv * 32 + g * 16 + qd * 4 + r) * CDIM + h * DH;
#pragma unroll
            for (int nt = 0; nt < 3; ++nt)
                ob[row + nt * 16 + l16] = __float2bfloat16(o[g][nt][r] * inv);
        }
}

// ---------------------------------------------------------------------------
// transpose (M,C) -> (B,C,H,W)
// ---------------------------------------------------------------------------
__global__ void transpose_kernel(const float* __restrict__ t, float* __restrict__ out) {
    __shared__ float tile[32][33];
    int b = blockIdx.z;
    int n0 = blockIdx.x * 32;
    int c0 = blockIdx.y * 32;
    int tx = threadIdx.x & 31;
    int ty = threadIdx.x >> 5;
    for (int i = ty; i < 32; i += 8)
        tile[i][tx] = t[(size_t)(b * NPIX + n0 + i) * CDIM + c0 + tx];
    __syncthreads();
    for (int i = ty; i < 32; i += 8)
        out[(size_t)(b * CDIM + c0 + i) * NPIX + n0 + tx] = tile[tx][i];
}

// ---------------------------------------------------------------------------
extern "C" void kernel_launch(void* const* d_in, const int* in_sizes, int n_in,
                              void* d_out, int out_size, void* d_ws, size_t ws_size,
                              hipStream_t stream) {
    const float* x = (const float*)d_in[0];
    const float* pos_w = (const float*)d_in[1];
    const float* pos_b = (const float*)d_in[2];
    const float* g1 = (const float*)d_in[3];
    const float* b1 = (const float*)d_in[4];
    const float* wqkv = (const float*)d_in[5];
    const float* bqkv = (const float*)d_in[6];
    const float* wproj = (const float*)d_in[7];
    const float* bproj = (const float*)d_in[8];
    const float* g2 = (const float*)d_in[9];
    const float* b2 = (const float*)d_in[10];
    const float* w1 = (const float*)d_in[11];
    const float* bf1 = (const float*)d_in[12];
    const float* w2 = (const float*)d_in[13];
    const float* bf2 = (const float*)d_in[14];
    float* out = (float*)d_out;

    char* ws = (char*)d_ws;
    float* t = (float*)ws;
    __hip_bfloat16* xn = (__hip_bfloat16*)(ws + 25165824);
    u16* vTb = (u16*)xn;  // vT reuses xn (xn dead after qkv GEMM, vT dead before LN2)
    __hip_bfloat16* wqkvT = (__hip_bfloat16*)(ws + 37748736);
    __hip_bfloat16* wprojT = (__hip_bfloat16*)(ws + 38633472);
    __hip_bfloat16* w1T = (__hip_bfloat16*)(ws + 38928384);
    __hip_bfloat16* w2T = (__hip_bfloat16*)(ws + 40108032);
    char* big = ws + 41287680;
    u16* qkvb = (u16*)big;
    __hip_bfloat16* obb = (__hip_bfloat16*)(big + 37748736);
    u16* hb = (u16*)big;

    wt_kernel<<<dim3(QKVN / 32, CDIM / 32), 256, 0, stream>>>(wqkv, wqkvT, CDIM, QKVN);
    wt_kernel<<<dim3(CDIM / 32, CDIM / 32), 256, 0, stream>>>(wproj, wprojT, CDIM, CDIM);
    wt_kernel<<<dim3(FFN / 32, CDIM / 32), 256, 0, stream>>>(w1, w1T, CDIM, FFN);
    wt_kernel<<<dim3(CDIM / 32, FFN / 32), 256, 0, stream>>>(w2, w2T, FFN, CDIM);

    conv_pe_kernel<<<dim3(CDIM / 64, HH, BATCH), 256, 0, stream>>>(x, pos_w, pos_b, t);
    ln_kernel<<<MTOK, 128, 0, stream>>>(t, g1, b1, xn);
    gemm_bf16<128, 0, 0, 1><<<dim3(QKVN / 128, MTOK / 128), 256, 0, stream>>>(
        (const u16*)xn, (const u16*)wqkvT, bqkv, nullptr, qkvb, QKVN, CDIM);
    vtrans_kernel<<<dim3(NPIX / 128, NHEADS, BATCH), 256, 0, stream>>>(qkvb, vTb);
    attn_kernel<<<dim3(1024), 256, 0, stream>>>(qkvb, vTb, obb);
    gemm_bf16<64, 1, 0, 0><<<dim3(CDIM / 64, MTOK / 128), 256, 0, stream>>>(
        (const u16*)obb, (const u16*)wprojT, bproj, t, t, CDIM, CDIM);
    ln_kernel<<<MTOK, 128, 0, stream>>>(t, g2, b2, xn);
    gemm_bf16<128, 0, 1, 1><<<dim3(FFN / 128, MTOK / 128), 256, 0, stream>>>(
        (const u16*)xn, (const u16*)w1T, bf1, nullptr, hb, FFN, CDIM);
    gemm_bf16<64, 1, 0, 0><<<dim3(CDIM / 64, MTOK / 128), 256, 0, stream>>>(
        (const u16*)hb, (const u16*)w2T, bf2, t, t, CDIM, FFN);
    transpose_kernel<<<dim3(32, 12, BATCH), 256, 0, stream>>>(t, out);
}

// Round 5
// 346.529 us; speedup vs baseline: 5.1932x; 1.0930x over previous
//
#include <hip/hip_runtime.h>
#include <hip/hip_bf16.h>
#include <math.h>

#define BATCH 16
#define CDIM 384
#define HH 32
#define WW 32
#define NPIX 1024
#define MTOK (BATCH * NPIX)  // 16384
#define NHEADS 8
#define DH 48
#define QKVN (3 * CDIM)      // 1152
#define FFN (4 * CDIM)       // 1536

typedef unsigned short u16;
typedef unsigned int u32;
typedef __attribute__((ext_vector_type(8))) short short8;
typedef __attribute__((ext_vector_type(4))) float floatx4;

#define MFMA16(a, b, c) __builtin_amdgcn_mfma_f32_16x16x32_bf16(a, b, c, 0, 0, 0)

// async global->LDS 16B copy; LDS dest must be wave-uniform base + lane*16
__device__ __forceinline__ void gl2lds16(const void* g, void* l) {
    __builtin_amdgcn_global_load_lds(
        (const __attribute__((address_space(1))) void*)g,
        (__attribute__((address_space(3))) void*)l, 16, 0, 0);
}

// ---------------------------------------------------------------------------
// depthwise 3x3 conv + identity + pos bias -> t[(b*N+p)*C+c], coalesced writes.
// ---------------------------------------------------------------------------
__global__ __launch_bounds__(256) void conv_pe_kernel(const float* __restrict__ x,
                                                      const float* __restrict__ pos_w,
                                                      const float* __restrict__ pos_b,
                                                      float* __restrict__ t) {
    __shared__ float xs[64][100];
    __shared__ float os[32][68];
    const int cg = blockIdx.x, h = blockIdx.y, b = blockIdx.z;
    const int tid = threadIdx.x;
    const int c0 = cg * 64;

#pragma unroll
    for (int it = 0; it < 6; ++it) {
        int task = tid + it * 256;
        int c = task / 24, rem = task % 24;
        int row = rem >> 3, f4 = rem & 7;
        int hh = h + row - 1;
        float4 v = {0.f, 0.f, 0.f, 0.f};
        if (hh >= 0 && hh < HH)
            v = *(const float4*)(x + (((size_t)(b * CDIM + c0 + c) * HH + hh) * WW + f4 * 4));
        *(float4*)&xs[c][row * 32 + f4 * 4] = v;
    }
    __syncthreads();

    const int c = tid >> 2, w0 = (tid & 3) * 8;
    float wgt[9];
#pragma unroll
    for (int i = 0; i < 9; ++i) wgt[i] = pos_w[(c0 + c) * 9 + i];
    const float pb = pos_b[c0 + c];
#pragma unroll
    for (int wi = 0; wi < 8; ++wi) {
        int w = w0 + wi;
        float acc = 0.f;
#pragma unroll
        for (int r = 0; r < 3; ++r)
#pragma unroll
            for (int kw = 0; kw < 3; ++kw) {
                int w2 = w + kw - 1;
                if (w2 >= 0 && w2 < WW) acc += xs[c][r * 32 + w2] * wgt[r * 3 + kw];
            }
        os[w][c] = xs[c][32 + w] + acc + pb;
    }
    __syncthreads();

    float* dstb = t + (size_t)(b * NPIX + h * 32) * CDIM + c0;
#pragma unroll
    for (int it = 0; it < 2; ++it) {
        int task = tid + it * 256;
        int px = task >> 4, f4 = task & 15;
        *(float4*)(dstb + (size_t)px * CDIM + f4 * 4) = *(const float4*)&os[px][f4 * 4];
    }
}

// ---------------------------------------------------------------------------
// row LayerNorm over C=384, bf16 output. 128 threads/row.
// ---------------------------------------------------------------------------
__global__ void ln_kernel(const float* __restrict__ in,
                          const float* __restrict__ g,
                          const float* __restrict__ bta,
                          __hip_bfloat16* __restrict__ out) {
    int m = blockIdx.x;
    const float* row = in + (size_t)m * CDIM;
    int tid = threadIdx.x;
    float v0 = row[tid], v1 = row[tid + 128], v2 = row[tid + 256];
    float s = v0 + v1 + v2;
    float ss = v0 * v0 + v1 * v1 + v2 * v2;
#pragma unroll
    for (int off = 32; off > 0; off >>= 1) {
        s += __shfl_down(s, off, 64);
        ss += __shfl_down(ss, off, 64);
    }
    __shared__ float red[4];
    if ((tid & 63) == 0) { red[tid >> 6] = s; red[2 + (tid >> 6)] = ss; }
    __syncthreads();
    float sum = red[0] + red[1], sumsq = red[2] + red[3];
    float mu = sum * (1.f / CDIM);
    float var = sumsq * (1.f / CDIM) - mu * mu;
    float rstd = rsqrtf(var + 1e-5f);
    __hip_bfloat16* orow = out + (size_t)m * CDIM;
    orow[tid]       = __float2bfloat16((v0 - mu) * rstd * g[tid] + bta[tid]);
    orow[tid + 128] = __float2bfloat16((v1 - mu) * rstd * g[tid + 128] + bta[tid + 128]);
    orow[tid + 256] = __float2bfloat16((v2 - mu) * rstd * g[tid + 256] + bta[tid + 256]);
}

// ---------------------------------------------------------------------------
// weight transpose+cast: Wt[n][k] = bf16(W[k][n]).
// ---------------------------------------------------------------------------
__global__ void wt_kernel(const float* __restrict__ W, __hip_bfloat16* __restrict__ Wt,
                          int K, int N) {
    __shared__ float tile[32][33];
    int n0 = blockIdx.x * 32, k0 = blockIdx.y * 32;
    int tx = threadIdx.x & 31, ty = threadIdx.x >> 5;
    for (int i = ty; i < 32; i += 8) tile[i][tx] = W[(size_t)(k0 + i) * N + n0 + tx];
    __syncthreads();
    for (int i = ty; i < 32; i += 8)
        Wt[(size_t)(n0 + i) * K + k0 + tx] = __float2bfloat16(tile[tx][i]);
}

// ---------------------------------------------------------------------------
// V transpose: vT[(b*8+h)*48+d][key] = qkv[b][key][2C + h*48 + d]  (bf16)
// ---------------------------------------------------------------------------
__global__ __launch_bounds__(256) void vtrans_kernel(const u16* __restrict__ qkv,
                                                     u16* __restrict__ vT) {
    __shared__ u16 Vl[48][136];
    const int kt = blockIdx.x, h = blockIdx.y, b = blockIdx.z;
    const int tid = threadIdx.x;
    const size_t base = (size_t)b * NPIX * QKVN + 2 * CDIM + (size_t)h * DH;
#pragma unroll
    for (int it = 0; it < 3; ++it) {
        int task = tid + it * 256;
        int key = task / 6, ch = task - key * 6;
        short8 v = *(const short8*)(qkv + base + (size_t)(kt * 128 + key) * QKVN + ch * 8);
#pragma unroll
        for (int i = 0; i < 8; ++i) Vl[ch * 8 + i][key] = (u16)v[i];
    }
    __syncthreads();
    u16* dst = vT + (size_t)(b * NHEADS + h) * DH * NPIX + (size_t)kt * 128;
#pragma unroll
    for (int it = 0; it < 3; ++it) {
        int task = tid + it * 256;
        int d = task >> 4, ch = task & 15;
        short8 v = *(const short8*)&Vl[d][ch * 8];
        *(short8*)(dst + (size_t)d * NPIX + ch * 8) = v;
    }
}

// ---------------------------------------------------------------------------
// bf16 MFMA GEMM, latency-optimized: BM=128, BN=64, BK=64 (2 chunk planes),
// double-buffered LDS (one barrier per K-step, prefetch issued before compute),
// XCD-swizzled linear grid (M-slab per XCD -> weights L2-resident).
// 4 waves (2x2): wave tile 64 rows x 32 cols; 16 MFMA per K-step.
// ---------------------------------------------------------------------------
template <int RES, int ACT, int OUTBF>
__global__ __launch_bounds__(256) void gemm_bf16(
    const u16* __restrict__ A, const u16* __restrict__ Bt,
    const float* __restrict__ bias, const float* __restrict__ Res,
    void* __restrict__ Cout, int N, int K) {
    __shared__ u16 As[2][2][128 * 32];  // [dbuf][kchunk][row*32+col]  32 KB
    __shared__ u16 Bs[2][2][64 * 32];   //                             16 KB
    const int tid = threadIdx.x;
    const int lane = tid & 63;
    const int wv = tid >> 6;
    const int qd = lane >> 4;
    const int l16 = lane & 15;
    const int wy = wv >> 1, wx = wv & 1;

    // XCD swizzle: Mb=128 always; xcd = id&7 owns M-slab of 16 row-blocks
    const int id = blockIdx.x;
    const int xcd = id & 7, j = id >> 3;
    const int m0 = (xcd * 16 + (j & 15)) * 128;
    const int n0 = (j >> 4) * 64;

    // staging map: thread covers A rows (tid>>2) and (tid>>2)+64, B row (tid>>2),
    // 8 bf16 at col (tid&3)*8 within each 32-col chunk plane.
    const int rr = tid >> 2, cc = (tid & 3) * 8;
    const u16* Ag = A + (size_t)(m0 + rr) * K + cc;
    const u16* Bg = Bt + (size_t)(n0 + rr) * K + cc;

    const floatx4 fz = {0.f, 0.f, 0.f, 0.f};
    floatx4 acc[4][2];
#pragma unroll
    for (int i = 0; i < 4; ++i)
#pragma unroll
        for (int jj = 0; jj < 2; ++jj) acc[i][jj] = fz;

    auto stage = [&](int slot, int k0) {
#pragma unroll
        for (int kc = 0; kc < 2; ++kc) {
            gl2lds16(Ag + k0 + kc * 32, &As[slot][kc][0] + tid * 8);
            gl2lds16(Ag + (size_t)64 * K + k0 + kc * 32, &As[slot][kc][0] + 2048 + tid * 8);
            gl2lds16(Bg + k0 + kc * 32, &Bs[slot][kc][0] + tid * 8);
        }
    };

    stage(0, 0);
    const int iters = K >> 6;
    for (int it = 0; it < iters; ++it) {
        const int slot = it & 1;
        __syncthreads();  // slot data ready; slot^1 consumers (it-1) all done
        if (it + 1 < iters) stage(slot ^ 1, (it + 1) << 6);
#pragma unroll
        for (int kc = 0; kc < 2; ++kc) {
            short8 af[4], bfr[2];
#pragma unroll
            for (int i = 0; i < 4; ++i)
                af[i] = *(const short8*)(&As[slot][kc][0] + (wy * 64 + i * 16 + l16) * 32 + qd * 8);
#pragma unroll
            for (int jj = 0; jj < 2; ++jj)
                bfr[jj] = *(const short8*)(&Bs[slot][kc][0] + (wx * 32 + jj * 16 + l16) * 32 + qd * 8);
#pragma unroll
            for (int i = 0; i < 4; ++i)
#pragma unroll
                for (int jj = 0; jj < 2; ++jj) acc[i][jj] = MFMA16(af[i], bfr[jj], acc[i][jj]);
        }
    }

    // epilogue: lane holds D[row = qd*4+r][col = l16] per 16x16 tile
    const int colb = n0 + wx * 32 + l16;
    const int rowb = m0 + wy * 64 + qd * 4;
#pragma unroll
    for (int jj = 0; jj < 2; ++jj) {
        int col = colb + jj * 16;
        float bb = bias[col];
#pragma unroll
        for (int i = 0; i < 4; ++i) {
            int row = rowb + i * 16;
#pragma unroll
            for (int r = 0; r < 4; ++r) {
                float c = acc[i][jj][r] + bb;
                if (RES) c += Res[(size_t)(row + r) * N + col];
                if (ACT) c = 0.5f * c * (1.f + erff(c * 0.70710678118654752f));
                if (OUTBF)
                    ((__hip_bfloat16*)Cout)[(size_t)(row + r) * N + col] = __float2bfloat16(c);
                else
                    ((float*)Cout)[(size_t)(row + r) * N + col] = c;
            }
        }
    }
}

// ---------------------------------------------------------------------------
// MFMA flash attention, no-running-max softmax, deferred normalization.
// ---------------------------------------------------------------------------
__global__ __launch_bounds__(256) void attn_kernel(const u16* __restrict__ qkv,
                                                   const u16* __restrict__ vT,
                                                   __hip_bfloat16* __restrict__ ob) {
    const int id = blockIdx.x;
    const int h = id & 7;
    const int b = (id >> 3) & 15;
    const int qb = id >> 7;
    const int tid = threadIdx.x;
    const int lane = tid & 63, wv = tid >> 6;
    const int qd = lane >> 4, l16 = lane & 15;

    __shared__ u16 Kl[65][48];
    __shared__ u16 Vt[48][72];
    __shared__ __hip_bfloat16 Pl[4][32][72];

    if (tid < 24) ((u32*)&Kl[64][0])[tid] = 0;

    const size_t bh = (size_t)b * NPIX * QKVN + (size_t)h * DH;
    const u16* vtb = vT + (size_t)(b * NHEADS + h) * DH * NPIX;

    short8 qf[2][2];
    const short8 z8 = {0, 0, 0, 0, 0, 0, 0, 0};
#pragma unroll
    for (int g = 0; g < 2; ++g) {
        const u16* gq = qkv + bh + (size_t)(qb * 128 + wv * 32 + g * 16 + l16) * QKVN;
        qf[g][0] = *(const short8*)(gq + qd * 8);
        qf[g][1] = (qd < 2) ? *(const short8*)(gq + 32 + qd * 8) : z8;
    }

    const floatx4 fz = {0.f, 0.f, 0.f, 0.f};
    floatx4 o[2][3];
    float lsum[2][4];
#pragma unroll
    for (int g = 0; g < 2; ++g) {
#pragma unroll
        for (int nt = 0; nt < 3; ++nt) o[g][nt] = fz;
#pragma unroll
        for (int r = 0; r < 4; ++r) lsum[g][r] = 0.f;
    }
    const float scale = 0.14433756729740643f;

    for (int kt = 0; kt < 16; ++kt) {
        __syncthreads();
        {
            const size_t kbase = bh + (size_t)(kt * 64) * QKVN + CDIM;
            int key = tid / 6, ch = tid - key * 6;
            gl2lds16(qkv + kbase + (size_t)key * QKVN + ch * 8, &Kl[0][0] + tid * 8);
            if (tid < 128) {
                int t2 = tid + 256;
                int k2 = t2 / 6, c2 = t2 - k2 * 6;
                gl2lds16(qkv + kbase + (size_t)k2 * QKVN + c2 * 8, &Kl[0][0] + t2 * 8);
            }
            int d = tid >> 3, vc = tid & 7;
            short8 v0 = *(const short8*)(vtb + (size_t)d * NPIX + kt * 64 + vc * 8);
            *(short8*)&Vt[d][vc * 8] = v0;
            if (tid < 128) {
                int d1 = (tid + 256) >> 3;
                short8 v1 = *(const short8*)(vtb + (size_t)d1 * NPIX + kt * 64 + vc * 8);
                *(short8*)&Vt[d1][vc * 8] = v1;
            }
        }
        __syncthreads();

        short8 kl[4], kh[4];
#pragma unroll
        for (int t = 0; t < 4; ++t) {
            const u16* kr = &Kl[0][0] + (t * 16 + l16) * 48;
            kl[t] = *(const short8*)(kr + qd * 8);
            kh[t] = *(const short8*)(kr + 32 + qd * 8);
        }
        floatx4 s[2][4];
#pragma unroll
        for (int g = 0; g < 2; ++g)
#pragma unroll
            for (int t = 0; t < 4; ++t) {
                floatx4 a = fz;
                a = MFMA16(qf[g][0], kl[t], a);
                a = MFMA16(qf[g][1], kh[t], a);
                s[g][t] = a;
            }

#pragma unroll
        for (int g = 0; g < 2; ++g)
#pragma unroll
            for (int t = 0; t < 4; ++t) {
#pragma unroll
                for (int r = 0; r < 4; ++r) {
                    float p = __expf(s[g][t][r] * scale);
                    Pl[wv][g * 16 + qd * 4 + r][t * 16 + l16] = __float2bfloat16(p);
                    lsum[g][r] += p;
                }
            }

        short8 vl[3], vh[3];
#pragma unroll
        for (int nt = 0; nt < 3; ++nt) {
            const u16* vr = &Vt[0][0] + (nt * 16 + l16) * 72;
            vl[nt] = *(const short8*)(vr + qd * 8);
            vh[nt] = *(const short8*)(vr + 32 + qd * 8);
        }
#pragma unroll
        for (int g = 0; g < 2; ++g) {
            const __hip_bfloat16* prr = &Pl[wv][g * 16 + l16][0];
            short8 ap0 = *(const short8*)(prr + qd * 8);
            short8 ap1 = *(const short8*)(prr + 32 + qd * 8);
#pragma unroll
            for (int nt = 0; nt < 3; ++nt) {
                o[g][nt] = MFMA16(ap0, vl[nt], o[g][nt]);
                o[g][nt] = MFMA16(ap1, vh[nt], o[g][nt]);
            }
        }
    }

#pragma unroll
    for (int g = 0; g < 2; ++g)
#pragma unroll
        for (int r = 0; r < 4; ++r) {
            float l = lsum[g][r];
            l += __shfl_xor(l, 1, 64);
            l += __shfl_xor(l, 2, 64);
            l += __shfl_xor(l, 4, 64);
            l += __shfl_xor(l, 8, 64);
            float inv = 1.f / l;
            size_t row = (size_t)(b * NPIX + qb * 128 + wv * 32 + g * 16 + qd * 4 + r) * CDIM + h * DH;
#pragma unroll
            for (int nt = 0; nt < 3; ++nt)
                ob[row + nt * 16 + l16] = __float2bfloat16(o[g][nt][r] * inv);
        }
}

// ---------------------------------------------------------------------------
// transpose (M,C) -> (B,C,H,W), float4 stores
// ---------------------------------------------------------------------------
__global__ void transpose_kernel(const float* __restrict__ t, float* __restrict__ out) {
    __shared__ float tile[32][33];
    int b = blockIdx.z;
    int n0 = blockIdx.x * 32;
    int c0 = blockIdx.y * 32;
    int tx = threadIdx.x & 31;
    int ty = threadIdx.x >> 5;
    for (int i = ty; i < 32; i += 8)
        tile[i][tx] = t[(size_t)(b * NPIX + n0 + i) * CDIM + c0 + tx];
    __syncthreads();
    int c = threadIdx.x >> 3, f4 = threadIdx.x & 7;
    float4 v;
    v.x = tile[f4 * 4 + 0][c];
    v.y = tile[f4 * 4 + 1][c];
    v.z = tile[f4 * 4 + 2][c];
    v.w = tile[f4 * 4 + 3][c];
    *(float4*)(out + (size_t)(b * CDIM + c0 + c) * NPIX + n0 + f4 * 4) = v;
}

// ---------------------------------------------------------------------------
extern "C" void kernel_launch(void* const* d_in, const int* in_sizes, int n_in,
                              void* d_out, int out_size, void* d_ws, size_t ws_size,
                              hipStream_t stream) {
    const float* x = (const float*)d_in[0];
    const float* pos_w = (const float*)d_in[1];
    const float* pos_b = (const float*)d_in[2];
    const float* g1 = (const float*)d_in[3];
    const float* b1 = (const float*)d_in[4];
    const float* wqkv = (const float*)d_in[5];
    const float* bqkv = (const float*)d_in[6];
    const float* wproj = (const float*)d_in[7];
    const float* bproj = (const float*)d_in[8];
    const float* g2 = (const float*)d_in[9];
    const float* b2 = (const float*)d_in[10];
    const float* w1 = (const float*)d_in[11];
    const float* bf1 = (const float*)d_in[12];
    const float* w2 = (const float*)d_in[13];
    const float* bf2 = (const float*)d_in[14];
    float* out = (float*)d_out;

    char* ws = (char*)d_ws;
    float* t = (float*)ws;
    __hip_bfloat16* xn = (__hip_bfloat16*)(ws + 25165824);
    u16* vTb = (u16*)xn;  // vT reuses xn (xn dead after qkv GEMM, vT dead before LN2)
    __hip_bfloat16* wqkvT = (__hip_bfloat16*)(ws + 37748736);
    __hip_bfloat16* wprojT = (__hip_bfloat16*)(ws + 38633472);
    __hip_bfloat16* w1T = (__hip_bfloat16*)(ws + 38928384);
    __hip_bfloat16* w2T = (__hip_bfloat16*)(ws + 40108032);
    char* big = ws + 41287680;
    u16* qkvb = (u16*)big;
    __hip_bfloat16* obb = (__hip_bfloat16*)(big + 37748736);
    u16* hb = (u16*)big;

    wt_kernel<<<dim3(QKVN / 32, CDIM / 32), 256, 0, stream>>>(wqkv, wqkvT, CDIM, QKVN);
    wt_kernel<<<dim3(CDIM / 32, CDIM / 32), 256, 0, stream>>>(wproj, wprojT, CDIM, CDIM);
    wt_kernel<<<dim3(FFN / 32, CDIM / 32), 256, 0, stream>>>(w1, w1T, CDIM, FFN);
    wt_kernel<<<dim3(CDIM / 32, FFN / 32), 256, 0, stream>>>(w2, w2T, FFN, CDIM);

    conv_pe_kernel<<<dim3(CDIM / 64, HH, BATCH), 256, 0, stream>>>(x, pos_w, pos_b, t);
    ln_kernel<<<MTOK, 128, 0, stream>>>(t, g1, b1, xn);
    // grids: 128 M-blocks x (N/64) N-blocks, linear with XCD swizzle inside
    gemm_bf16<0, 0, 1><<<dim3(128 * (QKVN / 64)), 256, 0, stream>>>(
        (const u16*)xn, (const u16*)wqkvT, bqkv, nullptr, qkvb, QKVN, CDIM);
    vtrans_kernel<<<dim3(NPIX / 128, NHEADS, BATCH), 256, 0, stream>>>(qkvb, vTb);
    attn_kernel<<<dim3(1024), 256, 0, stream>>>(qkvb, vTb, obb);
    gemm_bf16<1, 0, 0><<<dim3(128 * (CDIM / 64)), 256, 0, stream>>>(
        (const u16*)obb, (const u16*)wprojT, bproj, t, t, CDIM, CDIM);
    ln_kernel<<<MTOK, 128, 0, stream>>>(t, g2, b2, xn);
    gemm_bf16<0, 1, 1><<<dim3(128 * (FFN / 64)), 256, 0, stream>>>(
        (const u16*)xn, (const u16*)w1T, bf1, nullptr, hb, FFN, CDIM);
    gemm_bf16<1, 0, 0><<<dim3(128 * (CDIM / 64)), 256, 0, stream>>>(
        (const u16*)hb, (const u16*)w2T, bf2, t, t, CDIM, FFN);
    transpose_kernel<<<dim3(32, 12, BATCH), 256, 0, stream>>>(t, out);
}

// Round 6
// 341.173 us; speedup vs baseline: 5.2747x; 1.0157x over previous
//
#include <hip/hip_runtime.h>
#include <hip/hip_bf16.h>
#include <math.h>

#define BATCH 16
#define CDIM 384
#define HH 32
#define WW 32
#define NPIX 1024
#define MTOK (BATCH * NPIX)  // 16384
#define NHEADS 8
#define DH 48
#define QKVN (3 * CDIM)      // 1152
#define FFN (4 * CDIM)       // 1536

typedef unsigned short u16;
typedef unsigned int u32;
typedef __attribute__((ext_vector_type(8))) short short8;
typedef __attribute__((ext_vector_type(4))) float floatx4;

#define MFMA16(a, b, c) __builtin_amdgcn_mfma_f32_16x16x32_bf16(a, b, c, 0, 0, 0)

// async global->LDS 16B copy; LDS dest must be wave-uniform base + lane*16
__device__ __forceinline__ void gl2lds16(const void* g, void* l) {
    __builtin_amdgcn_global_load_lds(
        (const __attribute__((address_space(1))) void*)g,
        (__attribute__((address_space(3))) void*)l, 16, 0, 0);
}

// ---------------------------------------------------------------------------
// depthwise 3x3 conv + identity + pos bias -> t[(b*N+p)*C+c], coalesced writes.
// ---------------------------------------------------------------------------
__global__ __launch_bounds__(256) void conv_pe_kernel(const float* __restrict__ x,
                                                      const float* __restrict__ pos_w,
                                                      const float* __restrict__ pos_b,
                                                      float* __restrict__ t) {
    __shared__ float xs[64][100];
    __shared__ float os[32][68];
    const int cg = blockIdx.x, h = blockIdx.y, b = blockIdx.z;
    const int tid = threadIdx.x;
    const int c0 = cg * 64;

#pragma unroll
    for (int it = 0; it < 6; ++it) {
        int task = tid + it * 256;
        int c = task / 24, rem = task % 24;
        int row = rem >> 3, f4 = rem & 7;
        int hh = h + row - 1;
        float4 v = {0.f, 0.f, 0.f, 0.f};
        if (hh >= 0 && hh < HH)
            v = *(const float4*)(x + (((size_t)(b * CDIM + c0 + c) * HH + hh) * WW + f4 * 4));
        *(float4*)&xs[c][row * 32 + f4 * 4] = v;
    }
    __syncthreads();

    const int c = tid >> 2, w0 = (tid & 3) * 8;
    float wgt[9];
#pragma unroll
    for (int i = 0; i < 9; ++i) wgt[i] = pos_w[(c0 + c) * 9 + i];
    const float pb = pos_b[c0 + c];
#pragma unroll
    for (int wi = 0; wi < 8; ++wi) {
        int w = w0 + wi;
        float acc = 0.f;
#pragma unroll
        for (int r = 0; r < 3; ++r)
#pragma unroll
            for (int kw = 0; kw < 3; ++kw) {
                int w2 = w + kw - 1;
                if (w2 >= 0 && w2 < WW) acc += xs[c][r * 32 + w2] * wgt[r * 3 + kw];
            }
        os[w][c] = xs[c][32 + w] + acc + pb;
    }
    __syncthreads();

    float* dstb = t + (size_t)(b * NPIX + h * 32) * CDIM + c0;
#pragma unroll
    for (int it = 0; it < 2; ++it) {
        int task = tid + it * 256;
        int px = task >> 4, f4 = task & 15;
        *(float4*)(dstb + (size_t)px * CDIM + f4 * 4) = *(const float4*)&os[px][f4 * 4];
    }
}

// ---------------------------------------------------------------------------
// row LayerNorm over C=384, bf16 output. 128 threads/row.
// ---------------------------------------------------------------------------
__global__ void ln_kernel(const float* __restrict__ in,
                          const float* __restrict__ g,
                          const float* __restrict__ bta,
                          __hip_bfloat16* __restrict__ out) {
    int m = blockIdx.x;
    const float* row = in + (size_t)m * CDIM;
    int tid = threadIdx.x;
    float v0 = row[tid], v1 = row[tid + 128], v2 = row[tid + 256];
    float s = v0 + v1 + v2;
    float ss = v0 * v0 + v1 * v1 + v2 * v2;
#pragma unroll
    for (int off = 32; off > 0; off >>= 1) {
        s += __shfl_down(s, off, 64);
        ss += __shfl_down(ss, off, 64);
    }
    __shared__ float red[4];
    if ((tid & 63) == 0) { red[tid >> 6] = s; red[2 + (tid >> 6)] = ss; }
    __syncthreads();
    float sum = red[0] + red[1], sumsq = red[2] + red[3];
    float mu = sum * (1.f / CDIM);
    float var = sumsq * (1.f / CDIM) - mu * mu;
    float rstd = rsqrtf(var + 1e-5f);
    __hip_bfloat16* orow = out + (size_t)m * CDIM;
    orow[tid]       = __float2bfloat16((v0 - mu) * rstd * g[tid] + bta[tid]);
    orow[tid + 128] = __float2bfloat16((v1 - mu) * rstd * g[tid + 128] + bta[tid + 128]);
    orow[tid + 256] = __float2bfloat16((v2 - mu) * rstd * g[tid + 256] + bta[tid + 256]);
}

// ---------------------------------------------------------------------------
// weight transpose+cast: Wt[n][k] = bf16(W[k][n]).
// ---------------------------------------------------------------------------
__global__ void wt_kernel(const float* __restrict__ W, __hip_bfloat16* __restrict__ Wt,
                          int K, int N) {
    __shared__ float tile[32][33];
    int n0 = blockIdx.x * 32, k0 = blockIdx.y * 32;
    int tx = threadIdx.x & 31, ty = threadIdx.x >> 5;
    for (int i = ty; i < 32; i += 8) tile[i][tx] = W[(size_t)(k0 + i) * N + n0 + tx];
    __syncthreads();
    for (int i = ty; i < 32; i += 8)
        Wt[(size_t)(n0 + i) * K + k0 + tx] = __float2bfloat16(tile[tx][i]);
}

// ---------------------------------------------------------------------------
// V transpose: vT[(b*8+h)*48+d][key] = qkv[b][key][2C + h*48 + d]  (bf16)
// ---------------------------------------------------------------------------
__global__ __launch_bounds__(256) void vtrans_kernel(const u16* __restrict__ qkv,
                                                     u16* __restrict__ vT) {
    __shared__ u16 Vl[48][136];
    const int kt = blockIdx.x, h = blockIdx.y, b = blockIdx.z;
    const int tid = threadIdx.x;
    const size_t base = (size_t)b * NPIX * QKVN + 2 * CDIM + (size_t)h * DH;
#pragma unroll
    for (int it = 0; it < 3; ++it) {
        int task = tid + it * 256;
        int key = task / 6, ch = task - key * 6;
        short8 v = *(const short8*)(qkv + base + (size_t)(kt * 128 + key) * QKVN + ch * 8);
#pragma unroll
        for (int i = 0; i < 8; ++i) Vl[ch * 8 + i][key] = (u16)v[i];
    }
    __syncthreads();
    u16* dst = vT + (size_t)(b * NHEADS + h) * DH * NPIX + (size_t)kt * 128;
#pragma unroll
    for (int it = 0; it < 3; ++it) {
        int task = tid + it * 256;
        int d = task >> 4, ch = task & 15;
        short8 v = *(const short8*)&Vl[d][ch * 8];
        *(short8*)(dst + (size_t)d * NPIX + ch * 8) = v;
    }
}

// ---------------------------------------------------------------------------
// bf16 MFMA GEMM: C[M,N] = A[M,K] @ Bt[N,K]^T + bias (+Res) (+GELU)
// BM=128; BN/BK templated: big-N GEMMs use (128,32), N=384 GEMMs use (64,64).
// Double-buffered LDS, one barrier per K-step, XCD-swizzled linear grid.
// ---------------------------------------------------------------------------
template <int BN, int BK, int RES, int ACT, int OUTBF>
__global__ __launch_bounds__(256) void gemm_bf16(
    const u16* __restrict__ A, const u16* __restrict__ Bt,
    const float* __restrict__ bias, const float* __restrict__ Res,
    void* __restrict__ Cout, int N, int K) {
    constexpr int KC = BK / 32;   // 32-col chunk planes per K-step
    constexpr int NF = BN / 32;   // b-frags per wave
    __shared__ u16 As[2][KC][128 * 32];
    __shared__ u16 Bs[2][KC][BN * 32];
    const int tid = threadIdx.x;
    const int lane = tid & 63;
    const int wv = tid >> 6;
    const int qd = lane >> 4;
    const int l16 = lane & 15;
    const int wy = wv >> 1, wx = wv & 1;

    // XCD swizzle: xcd = id&7 owns a 16-block M-slab; weights+A-slab L2-resident
    const int id = blockIdx.x;
    const int xcd = id & 7, j = id >> 3;
    const int m0 = (xcd * 16 + (j & 15)) * 128;
    const int n0 = (j >> 4) * BN;

    const int rr = tid >> 2, cc = (tid & 3) * 8;
    const u16* Ag = A + (size_t)(m0 + rr) * K + cc;
    const u16* Bg = Bt + (size_t)(n0 + rr) * K + cc;

    const floatx4 fz = {0.f, 0.f, 0.f, 0.f};
    floatx4 acc[4][NF];
#pragma unroll
    for (int i = 0; i < 4; ++i)
#pragma unroll
        for (int jj = 0; jj < NF; ++jj) acc[i][jj] = fz;

    auto stage = [&](int slot, int k0) {
#pragma unroll
        for (int kc = 0; kc < KC; ++kc) {
            gl2lds16(Ag + k0 + kc * 32, &As[slot][kc][0] + tid * 8);
            gl2lds16(Ag + (size_t)64 * K + k0 + kc * 32, &As[slot][kc][0] + 2048 + tid * 8);
            gl2lds16(Bg + k0 + kc * 32, &Bs[slot][kc][0] + tid * 8);
            if (NF == 4) gl2lds16(Bg + (size_t)64 * K + k0 + kc * 32, &Bs[slot][kc][0] + 2048 + tid * 8);
        }
    };

    stage(0, 0);
    const int iters = K / BK;
    for (int it = 0; it < iters; ++it) {
        const int slot = it & 1;
        __syncthreads();  // slot data drained+visible; slot^1 consumers done
        if (it + 1 < iters) stage(slot ^ 1, (it + 1) * BK);
#pragma unroll
        for (int kc = 0; kc < KC; ++kc) {
            short8 af[4], bfr[NF];
#pragma unroll
            for (int i = 0; i < 4; ++i)
                af[i] = *(const short8*)(&As[slot][kc][0] + (wy * 64 + i * 16 + l16) * 32 + qd * 8);
#pragma unroll
            for (int jj = 0; jj < NF; ++jj)
                bfr[jj] = *(const short8*)(&Bs[slot][kc][0] + (wx * (BN / 2) + jj * 16 + l16) * 32 + qd * 8);
#pragma unroll
            for (int i = 0; i < 4; ++i)
#pragma unroll
                for (int jj = 0; jj < NF; ++jj) acc[i][jj] = MFMA16(af[i], bfr[jj], acc[i][jj]);
        }
    }

    const int colb = n0 + wx * (BN / 2) + l16;
    const int rowb = m0 + wy * 64 + qd * 4;
#pragma unroll
    for (int jj = 0; jj < NF; ++jj) {
        int col = colb + jj * 16;
        float bb = bias[col];
#pragma unroll
        for (int i = 0; i < 4; ++i) {
            int row = rowb + i * 16;
#pragma unroll
            for (int r = 0; r < 4; ++r) {
                float c = acc[i][jj][r] + bb;
                if (RES) c += Res[(size_t)(row + r) * N + col];
                if (ACT) c = 0.5f * c * (1.f + erff(c * 0.70710678118654752f));
                if (OUTBF)
                    ((__hip_bfloat16*)Cout)[(size_t)(row + r) * N + col] = __float2bfloat16(c);
                else
                    ((float*)Cout)[(size_t)(row + r) * N + col] = c;
            }
        }
    }
}

// ---------------------------------------------------------------------------
// MFMA flash attention, no-running-max softmax, deferred normalization.
// K LDS double-buffered (gl2lds prefetch one stage ahead); V reg-prefetched.
// ---------------------------------------------------------------------------
__global__ __launch_bounds__(256) void attn_kernel(const u16* __restrict__ qkv,
                                                   const u16* __restrict__ vT,
                                                   __hip_bfloat16* __restrict__ ob) {
    const int id = blockIdx.x;
    const int h = id & 7;
    const int b = (id >> 3) & 15;
    const int qb = id >> 7;
    const int tid = threadIdx.x;
    const int lane = tid & 63, wv = tid >> 6;
    const int qd = lane >> 4, l16 = lane & 15;

    __shared__ u16 Kl[2][65][48];            // dbuf [key][d], +1 safety row each
    __shared__ u16 Vt[48][72];               // [d][key]
    __shared__ __hip_bfloat16 Pl[4][32][72]; // per-wave P [qrow 32][key 64]

    if (tid < 24) { ((u32*)&Kl[0][64][0])[tid] = 0; ((u32*)&Kl[1][64][0])[tid] = 0; }

    const size_t bh = (size_t)b * NPIX * QKVN + (size_t)h * DH;
    const u16* vtb = vT + (size_t)(b * NHEADS + h) * DH * NPIX;

    auto stageK = [&](int kt, int slot) {
        const size_t kbase = bh + (size_t)(kt * 64) * QKVN + CDIM;
        int key = tid / 6, ch = tid - key * 6;
        gl2lds16(qkv + kbase + (size_t)key * QKVN + ch * 8, &Kl[slot][0][0] + tid * 8);
        if (tid < 128) {
            int t2 = tid + 256;
            int k2 = t2 / 6, c2 = t2 - k2 * 6;
            gl2lds16(qkv + kbase + (size_t)k2 * QKVN + c2 * 8, &Kl[slot][0][0] + t2 * 8);
        }
    };
    const int vd = tid >> 3, vc = tid & 7, vd1 = (tid + 256) >> 3;
    short8 vA, vB;
    auto loadV = [&](int kt) {
        vA = *(const short8*)(vtb + (size_t)vd * NPIX + kt * 64 + vc * 8);
        if (tid < 128) vB = *(const short8*)(vtb + (size_t)vd1 * NPIX + kt * 64 + vc * 8);
    };

    // Q fragments (A-operand), k padded 48->64 with zeros
    short8 qf[2][2];
    const short8 z8 = {0, 0, 0, 0, 0, 0, 0, 0};
#pragma unroll
    for (int g = 0; g < 2; ++g) {
        const u16* gq = qkv + bh + (size_t)(qb * 128 + wv * 32 + g * 16 + l16) * QKVN;
        qf[g][0] = *(const short8*)(gq + qd * 8);
        qf[g][1] = (qd < 2) ? *(const short8*)(gq + 32 + qd * 8) : z8;
    }

    const floatx4 fz = {0.f, 0.f, 0.f, 0.f};
    floatx4 o[2][3];
    float lsum[2][4];
#pragma unroll
    for (int g = 0; g < 2; ++g) {
#pragma unroll
        for (int nt = 0; nt < 3; ++nt) o[g][nt] = fz;
#pragma unroll
        for (int r = 0; r < 4; ++r) lsum[g][r] = 0.f;
    }
    const float scale = 0.14433756729740643f;

    stageK(0, 0);
    loadV(0);

    for (int kt = 0; kt < 16; ++kt) {
        const int cur = kt & 1;
        __syncthreads();  // (A) all waves done consuming Vt/Pl of stage kt-1
        *(short8*)&Vt[vd][vc * 8] = vA;
        if (tid < 128) *(short8*)&Vt[vd1][vc * 8] = vB;
        __syncthreads();  // (B) Vt visible; Kl[cur] gl2lds drained
        if (kt + 1 < 16) { stageK(kt + 1, cur ^ 1); loadV(kt + 1); }

        // QK^T from Kl[cur]
        short8 kl[4], kh[4];
#pragma unroll
        for (int t = 0; t < 4; ++t) {
            const u16* kr = &Kl[cur][0][0] + (t * 16 + l16) * 48;
            kl[t] = *(const short8*)(kr + qd * 8);
            kh[t] = *(const short8*)(kr + 32 + qd * 8);  // overread cols >=48 hit garbage * qf1=0
        }
        floatx4 s[2][4];
#pragma unroll
        for (int g = 0; g < 2; ++g)
#pragma unroll
            for (int t = 0; t < 4; ++t) {
                floatx4 a = fz;
                a = MFMA16(qf[g][0], kl[t], a);
                a = MFMA16(qf[g][1], kh[t], a);
                s[g][t] = a;
            }

        // p = exp(s*scale); per-lane partial sums; P to per-wave LDS
#pragma unroll
        for (int g = 0; g < 2; ++g)
#pragma unroll
            for (int t = 0; t < 4; ++t) {
#pragma unroll
                for (int r = 0; r < 4; ++r) {
                    float p = __expf(s[g][t][r] * scale);
                    Pl[wv][g * 16 + qd * 4 + r][t * 16 + l16] = __float2bfloat16(p);
                    lsum[g][r] += p;
                }
            }

        // PV (V frags reused across both Q sub-tiles; same-wave LDS RAW on Pl)
        short8 vl[3], vh[3];
#pragma unroll
        for (int nt = 0; nt < 3; ++nt) {
            const u16* vr = &Vt[0][0] + (nt * 16 + l16) * 72;
            vl[nt] = *(const short8*)(vr + qd * 8);
            vh[nt] = *(const short8*)(vr + 32 + qd * 8);
        }
#pragma unroll
        for (int g = 0; g < 2; ++g) {
            const __hip_bfloat16* prr = &Pl[wv][g * 16 + l16][0];
            short8 ap0 = *(const short8*)(prr + qd * 8);
            short8 ap1 = *(const short8*)(prr + 32 + qd * 8);
#pragma unroll
            for (int nt = 0; nt < 3; ++nt) {
                o[g][nt] = MFMA16(ap0, vl[nt], o[g][nt]);
                o[g][nt] = MFMA16(ap1, vh[nt], o[g][nt]);
            }
        }
    }

#pragma unroll
    for (int g = 0; g < 2; ++g)
#pragma unroll
        for (int r = 0; r < 4; ++r) {
            float l = lsum[g][r];
            l += __shfl_xor(l, 1, 64);
            l += __shfl_xor(l, 2, 64);
            l += __shfl_xor(l, 4, 64);
            l += __shfl_xor(l, 8, 64);
            float inv = 1.f / l;
            size_t row = (size_t)(b * NPIX + qb * 128 + wv * 32 + g * 16 + qd * 4 + r) * CDIM + h * DH;
#pragma unroll
            for (int nt = 0; nt < 3; ++nt)
                ob[row + nt * 16 + l16] = __float2bfloat16(o[g][nt][r] * inv);
        }
}

// ---------------------------------------------------------------------------
// transpose (M,C) -> (B,C,H,W), float4 stores
// ---------------------------------------------------------------------------
__global__ void transpose_kernel(const float* __restrict__ t, float* __restrict__ out) {
    __shared__ float tile[32][33];
    int b = blockIdx.z;
    int n0 = blockIdx.x * 32;
    int c0 = blockIdx.y * 32;
    int tx = threadIdx.x & 31;
    int ty = threadIdx.x >> 5;
    for (int i = ty; i < 32; i += 8)
        tile[i][tx] = t[(size_t)(b * NPIX + n0 + i) * CDIM + c0 + tx];
    __syncthreads();
    int c = threadIdx.x >> 3, f4 = threadIdx.x & 7;
    float4 v;
    v.x = tile[f4 * 4 + 0][c];
    v.y = tile[f4 * 4 + 1][c];
    v.z = tile[f4 * 4 + 2][c];
    v.w = tile[f4 * 4 + 3][c];
    *(float4*)(out + (size_t)(b * CDIM + c0 + c) * NPIX + n0 + f4 * 4) = v;
}

// ---------------------------------------------------------------------------
extern "C" void kernel_launch(void* const* d_in, const int* in_sizes, int n_in,
                              void* d_out, int out_size, void* d_ws, size_t ws_size,
                              hipStream_t stream) {
    const float* x = (const float*)d_in[0];
    const float* pos_w = (const float*)d_in[1];
    const float* pos_b = (const float*)d_in[2];
    const float* g1 = (const float*)d_in[3];
    const float* b1 = (const float*)d_in[4];
    const float* wqkv = (const float*)d_in[5];
    const float* bqkv = (const float*)d_in[6];
    const float* wproj = (const float*)d_in[7];
    const float* bproj = (const float*)d_in[8];
    const float* g2 = (const float*)d_in[9];
    const float* b2 = (const float*)d_in[10];
    const float* w1 = (const float*)d_in[11];
    const float* bf1 = (const float*)d_in[12];
    const float* w2 = (const float*)d_in[13];
    const float* bf2 = (const float*)d_in[14];
    float* out = (float*)d_out;

    char* ws = (char*)d_ws;
    float* t = (float*)ws;
    __hip_bfloat16* xn = (__hip_bfloat16*)(ws + 25165824);
    u16* vTb = (u16*)xn;  // vT reuses xn (xn dead after qkv GEMM, vT dead before LN2)
    __hip_bfloat16* wqkvT = (__hip_bfloat16*)(ws + 37748736);
    __hip_bfloat16* wprojT = (__hip_bfloat16*)(ws + 38633472);
    __hip_bfloat16* w1T = (__hip_bfloat16*)(ws + 38928384);
    __hip_bfloat16* w2T = (__hip_bfloat16*)(ws + 40108032);
    char* big = ws + 41287680;
    u16* qkvb = (u16*)big;
    __hip_bfloat16* obb = (__hip_bfloat16*)(big + 37748736);
    u16* hb = (u16*)big;

    wt_kernel<<<dim3(QKVN / 32, CDIM / 32), 256, 0, stream>>>(wqkv, wqkvT, CDIM, QKVN);
    wt_kernel<<<dim3(CDIM / 32, CDIM / 32), 256, 0, stream>>>(wproj, wprojT, CDIM, CDIM);
    wt_kernel<<<dim3(FFN / 32, CDIM / 32), 256, 0, stream>>>(w1, w1T, CDIM, FFN);
    wt_kernel<<<dim3(CDIM / 32, FFN / 32), 256, 0, stream>>>(w2, w2T, FFN, CDIM);

    conv_pe_kernel<<<dim3(CDIM / 64, HH, BATCH), 256, 0, stream>>>(x, pos_w, pos_b, t);
    ln_kernel<<<MTOK, 128, 0, stream>>>(t, g1, b1, xn);
    gemm_bf16<128, 32, 0, 0, 1><<<dim3(128 * (QKVN / 128)), 256, 0, stream>>>(
        (const u16*)xn, (const u16*)wqkvT, bqkv, nullptr, qkvb, QKVN, CDIM);
    vtrans_kernel<<<dim3(NPIX / 128, NHEADS, BATCH), 256, 0, stream>>>(qkvb, vTb);
    attn_kernel<<<dim3(1024), 256, 0, stream>>>(qkvb, vTb, obb);
    gemm_bf16<64, 64, 1, 0, 0><<<dim3(128 * (CDIM / 64)), 256, 0, stream>>>(
        (const u16*)obb, (const u16*)wprojT, bproj, t, t, CDIM, CDIM);
    ln_kernel<<<MTOK, 128, 0, stream>>>(t, g2, b2, xn);
    gemm_bf16<128, 32, 0, 1, 1><<<dim3(128 * (FFN / 128)), 256, 0, stream>>>(
        (const u16*)xn, (const u16*)w1T, bf1, nullptr, hb, FFN, CDIM);
    gemm_bf16<64, 64, 1, 0, 0><<<dim3(128 * (CDIM / 64)), 256, 0, stream>>>(
        (const u16*)hb, (const u16*)w2T, bf2, t, t, CDIM, FFN);
    transpose_kernel<<<dim3(32, 12, BATCH), 256, 0, stream>>>(t, out);
}

// Round 7
// 340.035 us; speedup vs baseline: 5.2924x; 1.0033x over previous
//
#include <hip/hip_runtime.h>
#include <hip/hip_bf16.h>
#include <math.h>

#define BATCH 16
#define CDIM 384
#define HH 32
#define WW 32
#define NPIX 1024
#define MTOK (BATCH * NPIX)  // 16384
#define NHEADS 8
#define DH 48
#define QKVN (3 * CDIM)      // 1152
#define FFN (4 * CDIM)       // 1536

typedef unsigned short u16;
typedef unsigned int u32;
typedef __attribute__((ext_vector_type(8))) short short8;
typedef __attribute__((ext_vector_type(4))) float floatx4;

#define MFMA16(a, b, c) __builtin_amdgcn_mfma_f32_16x16x32_bf16(a, b, c, 0, 0, 0)

// async global->LDS 16B copy; LDS dest must be wave-uniform base + lane*16
__device__ __forceinline__ void gl2lds16(const void* g, void* l) {
    __builtin_amdgcn_global_load_lds(
        (const __attribute__((address_space(1))) void*)g,
        (__attribute__((address_space(3))) void*)l, 16, 0, 0);
}

// pack two floats to two bf16 (RNE-ish via +0x8000 bias) in one u32: low16=a, high16=b
__device__ __forceinline__ u32 pkbf(float a, float b) {
    u32 ua = __float_as_uint(a) + 0x8000u;
    u32 ub = __float_as_uint(b) + 0x8000u;
    return __builtin_amdgcn_perm(ub, ua, 0x07060302u);
}
__device__ __forceinline__ float bf2f(u16 h) { return __uint_as_float(((u32)h) << 16); }
__device__ __forceinline__ u16 f2bf(float f) {
    u32 u = __float_as_uint(f);
    return (u16)((u + 0x7FFFu + ((u >> 16) & 1u)) >> 16);
}

// ---------------------------------------------------------------------------
// depthwise 3x3 conv + identity + pos bias -> t[(b*N+p)*C+c], coalesced writes.
// ---------------------------------------------------------------------------
__global__ __launch_bounds__(256) void conv_pe_kernel(const float* __restrict__ x,
                                                      const float* __restrict__ pos_w,
                                                      const float* __restrict__ pos_b,
                                                      float* __restrict__ t) {
    __shared__ float xs[64][100];
    __shared__ float os[32][68];
    const int cg = blockIdx.x, h = blockIdx.y, b = blockIdx.z;
    const int tid = threadIdx.x;
    const int c0 = cg * 64;

#pragma unroll
    for (int it = 0; it < 6; ++it) {
        int task = tid + it * 256;
        int c = task / 24, rem = task % 24;
        int row = rem >> 3, f4 = rem & 7;
        int hh = h + row - 1;
        float4 v = {0.f, 0.f, 0.f, 0.f};
        if (hh >= 0 && hh < HH)
            v = *(const float4*)(x + (((size_t)(b * CDIM + c0 + c) * HH + hh) * WW + f4 * 4));
        *(float4*)&xs[c][row * 32 + f4 * 4] = v;
    }
    __syncthreads();

    const int c = tid >> 2, w0 = (tid & 3) * 8;
    float wgt[9];
#pragma unroll
    for (int i = 0; i < 9; ++i) wgt[i] = pos_w[(c0 + c) * 9 + i];
    const float pb = pos_b[c0 + c];
#pragma unroll
    for (int wi = 0; wi < 8; ++wi) {
        int w = w0 + wi;
        float acc = 0.f;
#pragma unroll
        for (int r = 0; r < 3; ++r)
#pragma unroll
            for (int kw = 0; kw < 3; ++kw) {
                int w2 = w + kw - 1;
                if (w2 >= 0 && w2 < WW) acc += xs[c][r * 32 + w2] * wgt[r * 3 + kw];
            }
        os[w][c] = xs[c][32 + w] + acc + pb;
    }
    __syncthreads();

    float* dstb = t + (size_t)(b * NPIX + h * 32) * CDIM + c0;
#pragma unroll
    for (int it = 0; it < 2; ++it) {
        int task = tid + it * 256;
        int px = task >> 4, f4 = task & 15;
        *(float4*)(dstb + (size_t)px * CDIM + f4 * 4) = *(const float4*)&os[px][f4 * 4];
    }
}

// ---------------------------------------------------------------------------
// row LayerNorm over C=384, bf16 output. 128 threads/row.
// ---------------------------------------------------------------------------
__global__ void ln_kernel(const float* __restrict__ in,
                          const float* __restrict__ g,
                          const float* __restrict__ bta,
                          __hip_bfloat16* __restrict__ out) {
    int m = blockIdx.x;
    const float* row = in + (size_t)m * CDIM;
    int tid = threadIdx.x;
    float v0 = row[tid], v1 = row[tid + 128], v2 = row[tid + 256];
    float s = v0 + v1 + v2;
    float ss = v0 * v0 + v1 * v1 + v2 * v2;
#pragma unroll
    for (int off = 32; off > 0; off >>= 1) {
        s += __shfl_down(s, off, 64);
        ss += __shfl_down(ss, off, 64);
    }
    __shared__ float red[4];
    if ((tid & 63) == 0) { red[tid >> 6] = s; red[2 + (tid >> 6)] = ss; }
    __syncthreads();
    float sum = red[0] + red[1], sumsq = red[2] + red[3];
    float mu = sum * (1.f / CDIM);
    float var = sumsq * (1.f / CDIM) - mu * mu;
    float rstd = rsqrtf(var + 1e-5f);
    __hip_bfloat16* orow = out + (size_t)m * CDIM;
    orow[tid]       = __float2bfloat16((v0 - mu) * rstd * g[tid] + bta[tid]);
    orow[tid + 128] = __float2bfloat16((v1 - mu) * rstd * g[tid + 128] + bta[tid + 128]);
    orow[tid + 256] = __float2bfloat16((v2 - mu) * rstd * g[tid + 256] + bta[tid + 256]);
}

// ---------------------------------------------------------------------------
// weight transpose+cast: Wt[n][k] = bf16(W[k][n]).
// ---------------------------------------------------------------------------
__global__ void wt_kernel(const float* __restrict__ W, __hip_bfloat16* __restrict__ Wt,
                          int K, int N) {
    __shared__ float tile[32][33];
    int n0 = blockIdx.x * 32, k0 = blockIdx.y * 32;
    int tx = threadIdx.x & 31, ty = threadIdx.x >> 5;
    for (int i = ty; i < 32; i += 8) tile[i][tx] = W[(size_t)(k0 + i) * N + n0 + tx];
    __syncthreads();
    for (int i = ty; i < 32; i += 8)
        Wt[(size_t)(n0 + i) * K + k0 + tx] = __float2bfloat16(tile[tx][i]);
}

// ---------------------------------------------------------------------------
// V transpose: vT[(b*8+h)*48+d][key] = qkv[b][key][2C + h*48 + d]  (bf16)
// ---------------------------------------------------------------------------
__global__ __launch_bounds__(256) void vtrans_kernel(const u16* __restrict__ qkv,
                                                     u16* __restrict__ vT) {
    __shared__ u16 Vl[48][136];
    const int kt = blockIdx.x, h = blockIdx.y, b = blockIdx.z;
    const int tid = threadIdx.x;
    const size_t base = (size_t)b * NPIX * QKVN + 2 * CDIM + (size_t)h * DH;
#pragma unroll
    for (int it = 0; it < 3; ++it) {
        int task = tid + it * 256;
        int key = task / 6, ch = task - key * 6;
        short8 v = *(const short8*)(qkv + base + (size_t)(kt * 128 + key) * QKVN + ch * 8);
#pragma unroll
        for (int i = 0; i < 8; ++i) Vl[ch * 8 + i][key] = (u16)v[i];
    }
    __syncthreads();
    u16* dst = vT + (size_t)(b * NHEADS + h) * DH * NPIX + (size_t)kt * 128;
#pragma unroll
    for (int it = 0; it < 3; ++it) {
        int task = tid + it * 256;
        int d = task >> 4, ch = task & 15;
        short8 v = *(const short8*)&Vl[d][ch * 8];
        *(short8*)(dst + (size_t)d * NPIX + ch * 8) = v;
    }
}

// ---------------------------------------------------------------------------
// bf16 MFMA GEMM: C[M,N] = A[M,K] @ Bt[N,K]^T + bias (+Res) (+GELU)
// Operand-swapped MFMA (computes C^T tiles) -> lane holds 4 consecutive COLUMNS
// -> float4 / packed-b64 epilogue. Double-buffered LDS, XCD-swizzled grid.
// ---------------------------------------------------------------------------
template <int BN, int BK, int RES, int ACT, int OUTBF>
__global__ __launch_bounds__(256) void gemm_bf16(
    const u16* __restrict__ A, const u16* __restrict__ Bt,
    const float* __restrict__ bias, const float* __restrict__ Res,
    void* __restrict__ Cout, int N, int K) {
    constexpr int KC = BK / 32;
    constexpr int NF = BN / 32;
    __shared__ u16 As[2][KC][128 * 32];
    __shared__ u16 Bs[2][KC][BN * 32];
    const int tid = threadIdx.x;
    const int lane = tid & 63;
    const int wv = tid >> 6;
    const int qd = lane >> 4;
    const int l16 = lane & 15;
    const int wy = wv >> 1, wx = wv & 1;

    const int id = blockIdx.x;
    const int xcd = id & 7, j = id >> 3;
    const int m0 = (xcd * 16 + (j & 15)) * 128;
    const int n0 = (j >> 4) * BN;

    const int rr = tid >> 2, cc = (tid & 3) * 8;
    const u16* Ag = A + (size_t)(m0 + rr) * K + cc;
    const u16* Bg = Bt + (size_t)(n0 + rr) * K + cc;

    const floatx4 fz = {0.f, 0.f, 0.f, 0.f};
    floatx4 acc[4][NF];
#pragma unroll
    for (int i = 0; i < 4; ++i)
#pragma unroll
        for (int jj = 0; jj < NF; ++jj) acc[i][jj] = fz;

    auto stage = [&](int slot, int k0) {
#pragma unroll
        for (int kc = 0; kc < KC; ++kc) {
            gl2lds16(Ag + k0 + kc * 32, &As[slot][kc][0] + tid * 8);
            gl2lds16(Ag + (size_t)64 * K + k0 + kc * 32, &As[slot][kc][0] + 2048 + tid * 8);
            gl2lds16(Bg + k0 + kc * 32, &Bs[slot][kc][0] + tid * 8);
            if (NF == 4) gl2lds16(Bg + (size_t)64 * K + k0 + kc * 32, &Bs[slot][kc][0] + 2048 + tid * 8);
        }
    };

    stage(0, 0);
    const int iters = K / BK;
    for (int it = 0; it < iters; ++it) {
        const int slot = it & 1;
        __syncthreads();
        if (it + 1 < iters) stage(slot ^ 1, (it + 1) * BK);
#pragma unroll
        for (int kc = 0; kc < KC; ++kc) {
            short8 af[4], bfr[NF];
#pragma unroll
            for (int i = 0; i < 4; ++i)
                af[i] = *(const short8*)(&As[slot][kc][0] + (wy * 64 + i * 16 + l16) * 32 + qd * 8);
#pragma unroll
            for (int jj = 0; jj < NF; ++jj)
                bfr[jj] = *(const short8*)(&Bs[slot][kc][0] + (wx * (BN / 2) + jj * 16 + l16) * 32 + qd * 8);
            // swapped operands: D = C^T tile; lane -> (col=qd*4+r, row=l16)
#pragma unroll
            for (int i = 0; i < 4; ++i)
#pragma unroll
                for (int jj = 0; jj < NF; ++jj) acc[i][jj] = MFMA16(bfr[jj], af[i], acc[i][jj]);
        }
    }

    // epilogue: lane writes row (i*16+l16), cols (jj*16+qd*4 .. +3) -> vectorized
    const int rowb = m0 + wy * 64 + l16;
    const int colb = n0 + wx * (BN / 2) + qd * 4;
#pragma unroll
    for (int jj = 0; jj < NF; ++jj) {
        int col = colb + jj * 16;
        float4 bb = *(const float4*)(bias + col);
#pragma unroll
        for (int i = 0; i < 4; ++i) {
            int row = rowb + i * 16;
            floatx4 a = acc[i][jj];
            float v0 = a[0] + bb.x, v1 = a[1] + bb.y, v2 = a[2] + bb.z, v3 = a[3] + bb.w;
            if (RES) {
                float4 rv = *(const float4*)(Res + (size_t)row * N + col);
                v0 += rv.x; v1 += rv.y; v2 += rv.z; v3 += rv.w;
            }
            if (ACT) {
                v0 = 0.5f * v0 * (1.f + erff(v0 * 0.70710678118654752f));
                v1 = 0.5f * v1 * (1.f + erff(v1 * 0.70710678118654752f));
                v2 = 0.5f * v2 * (1.f + erff(v2 * 0.70710678118654752f));
                v3 = 0.5f * v3 * (1.f + erff(v3 * 0.70710678118654752f));
            }
            if (OUTBF) {
                uint2 pk;
                pk.x = pkbf(v0, v1);
                pk.y = pkbf(v2, v3);
                *(uint2*)((__hip_bfloat16*)Cout + (size_t)row * N + col) = pk;
            } else {
                float4 st = {v0, v1, v2, v3};
                *(float4*)((float*)Cout + (size_t)row * N + col) = st;
            }
        }
    }
}

// ---------------------------------------------------------------------------
// MFMA flash attention, transposed compute: S^T = MFMA(K,Q), O^T = MFMA(V^T,P^T).
// No-max softmax (exp2, scale folded into Q), deferred normalization.
// P^T packed to b64 LDS stores; output packed b64. K LDS dbuf; V reg-prefetch.
// ---------------------------------------------------------------------------
__global__ __launch_bounds__(256) void attn_kernel(const u16* __restrict__ qkv,
                                                   const u16* __restrict__ vT,
                                                   __hip_bfloat16* __restrict__ ob) {
    const int id = blockIdx.x;
    const int h = id & 7;
    const int b = (id >> 3) & 15;
    const int qb = id >> 7;
    const int tid = threadIdx.x;
    const int lane = tid & 63, wv = tid >> 6;
    const int qd = lane >> 4, l16 = lane & 15;

    __shared__ u16 Kl[2][65][48];                    // dbuf [key][d], +1 safety row
    __shared__ __align__(16) u16 Vt[48][72];         // [d][key]
    __shared__ __align__(16) u16 Plt[4][16][72];     // per-wave P^T as [query][key]

    if (tid < 24) { ((u32*)&Kl[0][64][0])[tid] = 0; ((u32*)&Kl[1][64][0])[tid] = 0; }

    const size_t bh = (size_t)b * NPIX * QKVN + (size_t)h * DH;
    const u16* vtb = vT + (size_t)(b * NHEADS + h) * DH * NPIX;

    auto stageK = [&](int kt, int slot) {
        const size_t kbase = bh + (size_t)(kt * 64) * QKVN + CDIM;
        int key = tid / 6, ch = tid - key * 6;
        gl2lds16(qkv + kbase + (size_t)key * QKVN + ch * 8, &Kl[slot][0][0] + tid * 8);
        if (tid < 128) {
            int t2 = tid + 256;
            int k2 = t2 / 6, c2 = t2 - k2 * 6;
            gl2lds16(qkv + kbase + (size_t)k2 * QKVN + c2 * 8, &Kl[slot][0][0] + t2 * 8);
        }
    };
    const int vd = tid >> 3, vc = tid & 7, vd1 = (tid + 256) >> 3;
    short8 vA, vB;
    auto loadV = [&](int kt) {
        vA = *(const short8*)(vtb + (size_t)vd * NPIX + kt * 64 + vc * 8);
        if (tid < 128) vB = *(const short8*)(vtb + (size_t)vd1 * NPIX + kt * 64 + vc * 8);
    };

    // Q fragments (B-operand), k padded 48->64 with zeros; scale*log2e folded in
    const float qsc = 0.14433756729740643f * 1.4426950408889634f;
    short8 qf[2][2];
    const short8 z8 = {0, 0, 0, 0, 0, 0, 0, 0};
#pragma unroll
    for (int g = 0; g < 2; ++g) {
        const u16* gq = qkv + bh + (size_t)(qb * 128 + wv * 32 + g * 16 + l16) * QKVN;
        short8 q0 = *(const short8*)(gq + qd * 8);
        short8 q1 = (qd < 2) ? *(const short8*)(gq + 32 + qd * 8) : z8;
#pragma unroll
        for (int e = 0; e < 8; ++e) {
            q0[e] = (short)f2bf(bf2f((u16)q0[e]) * qsc);
            q1[e] = (short)f2bf(bf2f((u16)q1[e]) * qsc);
        }
        qf[g][0] = q0;
        qf[g][1] = q1;
    }

    const floatx4 fz = {0.f, 0.f, 0.f, 0.f};
    floatx4 o[2][3];
    float lsum[2] = {0.f, 0.f};
#pragma unroll
    for (int g = 0; g < 2; ++g)
#pragma unroll
        for (int nt = 0; nt < 3; ++nt) o[g][nt] = fz;

    stageK(0, 0);
    loadV(0);

    for (int kt = 0; kt < 16; ++kt) {
        const int cur = kt & 1;
        __syncthreads();  // (A) all waves done with Vt of stage kt-1
        *(short8*)&Vt[vd][vc * 8] = vA;
        if (tid < 128) *(short8*)&Vt[vd1][vc * 8] = vB;
        __syncthreads();  // (B) Vt visible; Kl[cur] gl2lds drained
        if (kt + 1 < 16) { stageK(kt + 1, cur ^ 1); loadV(kt + 1); }

        // K fragments (A-operand: m=key)
        short8 kl[4], kh[4];
#pragma unroll
        for (int t = 0; t < 4; ++t) {
            const u16* kr = &Kl[cur][0][0] + (t * 16 + l16) * 48;
            kl[t] = *(const short8*)(kr + qd * 8);
            kh[t] = *(const short8*)(kr + 32 + qd * 8);  // overread d>=48 * qf1=0
        }
        // V fragments (A-operand for PV: m=d), shared across both Q groups
        short8 vl[3], vh[3];
#pragma unroll
        for (int nt = 0; nt < 3; ++nt) {
            const u16* vr = &Vt[0][0] + (nt * 16 + l16) * 72;
            vl[nt] = *(const short8*)(vr + qd * 8);
            vh[nt] = *(const short8*)(vr + 32 + qd * 8);
        }

#pragma unroll
        for (int g = 0; g < 2; ++g) {
            // S^T tiles: lane -> (key = t*16+qd*4+r, query = l16)
#pragma unroll
            for (int t = 0; t < 4; ++t) {
                floatx4 a = fz;
                a = MFMA16(kl[t], qf[g][0], a);
                a = MFMA16(kh[t], qf[g][1], a);
                float p0 = __builtin_amdgcn_exp2f(a[0]);
                float p1 = __builtin_amdgcn_exp2f(a[1]);
                float p2 = __builtin_amdgcn_exp2f(a[2]);
                float p3 = __builtin_amdgcn_exp2f(a[3]);
                lsum[g] += (p0 + p1) + (p2 + p3);
                uint2 w;
                w.x = pkbf(p0, p1);
                w.y = pkbf(p2, p3);
                *(uint2*)&Plt[wv][l16][t * 16 + qd * 4] = w;  // P^T[query][key]
            }
            // PV: O^T accumulate (B-operand = P^T read back, same-wave RAW)
            short8 ap0 = *(const short8*)&Plt[wv][l16][qd * 8];
            short8 ap1 = *(const short8*)&Plt[wv][l16][32 + qd * 8];
#pragma unroll
            for (int nt = 0; nt < 3; ++nt) {
                o[g][nt] = MFMA16(vl[nt], ap0, o[g][nt]);
                o[g][nt] = MFMA16(vh[nt], ap1, o[g][nt]);
            }
        }
    }

    // epilogue: lane holds O^T[d=nt*16+qd*4+r][query=l16] -> 3 b64 stores per g
#pragma unroll
    for (int g = 0; g < 2; ++g) {
        float l = lsum[g];
        l += __shfl_xor(l, 16, 64);
        l += __shfl_xor(l, 32, 64);
        float inv = 1.f / l;
        __hip_bfloat16* orow =
            ob + (size_t)(b * NPIX + qb * 128 + wv * 32 + g * 16 + l16) * CDIM + h * DH;
#pragma unroll
        for (int nt = 0; nt < 3; ++nt) {
            float v0 = o[g][nt][0] * inv, v1 = o[g][nt][1] * inv;
            float v2 = o[g][nt][2] * inv, v3 = o[g][nt][3] * inv;
            uint2 w;
            w.x = pkbf(v0, v1);
            w.y = pkbf(v2, v3);
            *(uint2*)(orow + nt * 16 + qd * 4) = w;
        }
    }
}

// ---------------------------------------------------------------------------
// transpose (M,C) -> (B,C,H,W), float4 stores
// ---------------------------------------------------------------------------
__global__ void transpose_kernel(const float* __restrict__ t, float* __restrict__ out) {
    __shared__ float tile[32][33];
    int b = blockIdx.z;
    int n0 = blockIdx.x * 32;
    int c0 = blockIdx.y * 32;
    int tx = threadIdx.x & 31;
    int ty = threadIdx.x >> 5;
    for (int i = ty; i < 32; i += 8)
        tile[i][tx] = t[(size_t)(b * NPIX + n0 + i) * CDIM + c0 + tx];
    __syncthreads();
    int c = threadIdx.x >> 3, f4 = threadIdx.x & 7;
    float4 v;
    v.x = tile[f4 * 4 + 0][c];
    v.y = tile[f4 * 4 + 1][c];
    v.z = tile[f4 * 4 + 2][c];
    v.w = tile[f4 * 4 + 3][c];
    *(float4*)(out + (size_t)(b * CDIM + c0 + c) * NPIX + n0 + f4 * 4) = v;
}

// ---------------------------------------------------------------------------
extern "C" void kernel_launch(void* const* d_in, const int* in_sizes, int n_in,
                              void* d_out, int out_size, void* d_ws, size_t ws_size,
                              hipStream_t stream) {
    const float* x = (const float*)d_in[0];
    const float* pos_w = (const float*)d_in[1];
    const float* pos_b = (const float*)d_in[2];
    const float* g1 = (const float*)d_in[3];
    const float* b1 = (const float*)d_in[4];
    const float* wqkv = (const float*)d_in[5];
    const float* bqkv = (const float*)d_in[6];
    const float* wproj = (const float*)d_in[7];
    const float* bproj = (const float*)d_in[8];
    const float* g2 = (const float*)d_in[9];
    const float* b2 = (const float*)d_in[10];
    const float* w1 = (const float*)d_in[11];
    const float* bf1 = (const float*)d_in[12];
    const float* w2 = (const float*)d_in[13];
    const float* bf2 = (const float*)d_in[14];
    float* out = (float*)d_out;

    char* ws = (char*)d_ws;
    float* t = (float*)ws;
    __hip_bfloat16* xn = (__hip_bfloat16*)(ws + 25165824);
    u16* vTb = (u16*)xn;  // vT reuses xn (xn dead after qkv GEMM, vT dead before LN2)
    __hip_bfloat16* wqkvT = (__hip_bfloat16*)(ws + 37748736);
    __hip_bfloat16* wprojT = (__hip_bfloat16*)(ws + 38633472);
    __hip_bfloat16* w1T = (__hip_bfloat16*)(ws + 38928384);
    __hip_bfloat16* w2T = (__hip_bfloat16*)(ws + 40108032);
    char* big = ws + 41287680;
    u16* qkvb = (u16*)big;
    __hip_bfloat16* obb = (__hip_bfloat16*)(big + 37748736);
    u16* hb = (u16*)big;

    wt_kernel<<<dim3(QKVN / 32, CDIM / 32), 256, 0, stream>>>(wqkv, wqkvT, CDIM, QKVN);
    wt_kernel<<<dim3(CDIM / 32, CDIM / 32), 256, 0, stream>>>(wproj, wprojT, CDIM, CDIM);
    wt_kernel<<<dim3(FFN / 32, CDIM / 32), 256, 0, stream>>>(w1, w1T, CDIM, FFN);
    wt_kernel<<<dim3(CDIM / 32, FFN / 32), 256, 0, stream>>>(w2, w2T, FFN, CDIM);

    conv_pe_kernel<<<dim3(CDIM / 64, HH, BATCH), 256, 0, stream>>>(x, pos_w, pos_b, t);
    ln_kernel<<<MTOK, 128, 0, stream>>>(t, g1, b1, xn);
    gemm_bf16<128, 32, 0, 0, 1><<<dim3(128 * (QKVN / 128)), 256, 0, stream>>>(
        (const u16*)xn, (const u16*)wqkvT, bqkv, nullptr, qkvb, QKVN, CDIM);
    vtrans_kernel<<<dim3(NPIX / 128, NHEADS, BATCH), 256, 0, stream>>>(qkvb, vTb);
    attn_kernel<<<dim3(1024), 256, 0, stream>>>(qkvb, vTb, obb);
    gemm_bf16<64, 64, 1, 0, 0><<<dim3(128 * (CDIM / 64)), 256, 0, stream>>>(
        (const u16*)obb, (const u16*)wprojT, bproj, t, t, CDIM, CDIM);
    ln_kernel<<<MTOK, 128, 0, stream>>>(t, g2, b2, xn);
    gemm_bf16<128, 32, 0, 1, 1><<<dim3(128 * (FFN / 128)), 256, 0, stream>>>(
        (const u16*)xn, (const u16*)w1T, bf1, nullptr, hb, FFN, CDIM);
    gemm_bf16<64, 64, 1, 0, 0><<<dim3(128 * (CDIM / 64)), 256, 0, stream>>>(
        (const u16*)hb, (const u16*)w2T, bf2, t, t, CDIM, FFN);
    transpose_kernel<<<dim3(32, 12, BATCH), 256, 0, stream>>>(t, out);
}

// Round 8
// 319.356 us; speedup vs baseline: 5.6351x; 1.0648x over previous
//
#include <hip/hip_runtime.h>
#include <hip/hip_bf16.h>
#include <math.h>

#define BATCH 16
#define CDIM 384
#define HH 32
#define WW 32
#define NPIX 1024
#define MTOK (BATCH * NPIX)  // 16384
#define NHEADS 8
#define DH 48
#define QKVN (3 * CDIM)      // 1152
#define FFN (4 * CDIM)       // 1536

typedef unsigned short u16;
typedef unsigned int u32;
typedef __attribute__((ext_vector_type(8))) short short8;
typedef __attribute__((ext_vector_type(4))) float floatx4;

#define MFMA16(a, b, c) __builtin_amdgcn_mfma_f32_16x16x32_bf16(a, b, c, 0, 0, 0)

// async global->LDS 16B copy; LDS dest must be wave-uniform base + lane*16
__device__ __forceinline__ void gl2lds16(const void* g, void* l) {
    __builtin_amdgcn_global_load_lds(
        (const __attribute__((address_space(1))) void*)g,
        (__attribute__((address_space(3))) void*)l, 16, 0, 0);
}

// pack two floats to two bf16 (RNE via +rounding bias) in one u32: low16=a, high16=b
__device__ __forceinline__ u32 pkbf(float a, float b) {
    u32 ua = __float_as_uint(a) + 0x8000u;
    u32 ub = __float_as_uint(b) + 0x8000u;
    return __builtin_amdgcn_perm(ub, ua, 0x07060302u);
}
__device__ __forceinline__ float bf2f(u16 h) { return __uint_as_float(((u32)h) << 16); }
__device__ __forceinline__ u16 f2bf(float f) {
    u32 u = __float_as_uint(f);
    return (u16)((u + 0x7FFFu + ((u >> 16) & 1u)) >> 16);
}

// ---------------------------------------------------------------------------
// depthwise 3x3 conv + identity + pos bias -> t[(b*N+p)*C+c], coalesced writes.
// ---------------------------------------------------------------------------
__global__ __launch_bounds__(256) void conv_pe_kernel(const float* __restrict__ x,
                                                      const float* __restrict__ pos_w,
                                                      const float* __restrict__ pos_b,
                                                      float* __restrict__ t) {
    __shared__ float xs[64][100];
    __shared__ float os[32][68];
    const int cg = blockIdx.x, h = blockIdx.y, b = blockIdx.z;
    const int tid = threadIdx.x;
    const int c0 = cg * 64;

#pragma unroll
    for (int it = 0; it < 6; ++it) {
        int task = tid + it * 256;
        int c = task / 24, rem = task % 24;
        int row = rem >> 3, f4 = rem & 7;
        int hh = h + row - 1;
        float4 v = {0.f, 0.f, 0.f, 0.f};
        if (hh >= 0 && hh < HH)
            v = *(const float4*)(x + (((size_t)(b * CDIM + c0 + c) * HH + hh) * WW + f4 * 4));
        *(float4*)&xs[c][row * 32 + f4 * 4] = v;
    }
    __syncthreads();

    const int c = tid >> 2, w0 = (tid & 3) * 8;
    float wgt[9];
#pragma unroll
    for (int i = 0; i < 9; ++i) wgt[i] = pos_w[(c0 + c) * 9 + i];
    const float pb = pos_b[c0 + c];
#pragma unroll
    for (int wi = 0; wi < 8; ++wi) {
        int w = w0 + wi;
        float acc = 0.f;
#pragma unroll
        for (int r = 0; r < 3; ++r)
#pragma unroll
            for (int kw = 0; kw < 3; ++kw) {
                int w2 = w + kw - 1;
                if (w2 >= 0 && w2 < WW) acc += xs[c][r * 32 + w2] * wgt[r * 3 + kw];
            }
        os[w][c] = xs[c][32 + w] + acc + pb;
    }
    __syncthreads();

    float* dstb = t + (size_t)(b * NPIX + h * 32) * CDIM + c0;
#pragma unroll
    for (int it = 0; it < 2; ++it) {
        int task = tid + it * 256;
        int px = task >> 4, f4 = task & 15;
        *(float4*)(dstb + (size_t)px * CDIM + f4 * 4) = *(const float4*)&os[px][f4 * 4];
    }
}

// ---------------------------------------------------------------------------
// row LayerNorm over C=384, bf16 output. 128 threads/row.
// ---------------------------------------------------------------------------
__global__ void ln_kernel(const float* __restrict__ in,
                          const float* __restrict__ g,
                          const float* __restrict__ bta,
                          __hip_bfloat16* __restrict__ out) {
    int m = blockIdx.x;
    const float* row = in + (size_t)m * CDIM;
    int tid = threadIdx.x;
    float v0 = row[tid], v1 = row[tid + 128], v2 = row[tid + 256];
    float s = v0 + v1 + v2;
    float ss = v0 * v0 + v1 * v1 + v2 * v2;
#pragma unroll
    for (int off = 32; off > 0; off >>= 1) {
        s += __shfl_down(s, off, 64);
        ss += __shfl_down(ss, off, 64);
    }
    __shared__ float red[4];
    if ((tid & 63) == 0) { red[tid >> 6] = s; red[2 + (tid >> 6)] = ss; }
    __syncthreads();
    float sum = red[0] + red[1], sumsq = red[2] + red[3];
    float mu = sum * (1.f / CDIM);
    float var = sumsq * (1.f / CDIM) - mu * mu;
    float rstd = rsqrtf(var + 1e-5f);
    __hip_bfloat16* orow = out + (size_t)m * CDIM;
    orow[tid]       = __float2bfloat16((v0 - mu) * rstd * g[tid] + bta[tid]);
    orow[tid + 128] = __float2bfloat16((v1 - mu) * rstd * g[tid + 128] + bta[tid + 128]);
    orow[tid + 256] = __float2bfloat16((v2 - mu) * rstd * g[tid + 256] + bta[tid + 256]);
}

// ---------------------------------------------------------------------------
// all 4 weight transposes in ONE dispatch: Wt[n][k] = bf16(W[k][n]).
// block-range switch: wqkv 432 | wproj 144 | w1 576 | w2 576 tiles of 32x32.
// ---------------------------------------------------------------------------
__global__ void wt_all_kernel(const float* __restrict__ wqkv, const float* __restrict__ wproj,
                              const float* __restrict__ w1, const float* __restrict__ w2,
                              __hip_bfloat16* __restrict__ wqkvT, __hip_bfloat16* __restrict__ wprojT,
                              __hip_bfloat16* __restrict__ w1T, __hip_bfloat16* __restrict__ w2T) {
    __shared__ float tile[32][33];
    int id = blockIdx.x;
    const float* W;
    __hip_bfloat16* Wt;
    int K, N, tidx;
    if (id < 432)       { W = wqkv;  Wt = wqkvT;  K = 384;  N = 1152; tidx = id; }
    else if (id < 576)  { W = wproj; Wt = wprojT; K = 384;  N = 384;  tidx = id - 432; }
    else if (id < 1152) { W = w1;    Wt = w1T;    K = 384;  N = 1536; tidx = id - 576; }
    else                { W = w2;    Wt = w2T;    K = 1536; N = 384;  tidx = id - 1152; }
    int ntx = N / 32;
    int n0 = (tidx % ntx) * 32, k0 = (tidx / ntx) * 32;
    int tx = threadIdx.x & 31, ty = threadIdx.x >> 5;
    for (int i = ty; i < 32; i += 8) tile[i][tx] = W[(size_t)(k0 + i) * N + n0 + tx];
    __syncthreads();
    for (int i = ty; i < 32; i += 8)
        Wt[(size_t)(n0 + i) * K + k0 + tx] = __float2bfloat16(tile[tx][i]);
}

// ---------------------------------------------------------------------------
// V transpose with per-64-key-tile XOR swizzle: value V[d][key] stored at
// vT[(b,h)] + d*1024 + (key&~63) + ((((key>>3)&7) ^ (d&7))<<3) + (key&7).
// This makes the attn gl2lds LDS image bank-optimal without padding.
// ---------------------------------------------------------------------------
__global__ __launch_bounds__(256) void vtrans_kernel(const u16* __restrict__ qkv,
                                                     u16* __restrict__ vT) {
    __shared__ u16 Vl[48][136];
    const int kt = blockIdx.x, h = blockIdx.y, b = blockIdx.z;
    const int tid = threadIdx.x;
    const size_t base = (size_t)b * NPIX * QKVN + 2 * CDIM + (size_t)h * DH;
#pragma unroll
    for (int it = 0; it < 3; ++it) {
        int task = tid + it * 256;
        int key = task / 6, ch = task - key * 6;
        short8 v = *(const short8*)(qkv + base + (size_t)(kt * 128 + key) * QKVN + ch * 8);
#pragma unroll
        for (int i = 0; i < 8; ++i) Vl[ch * 8 + i][key] = (u16)v[i];
    }
    __syncthreads();
    u16* dst = vT + (size_t)(b * NHEADS + h) * DH * NPIX + (size_t)kt * 128;
#pragma unroll
    for (int it = 0; it < 3; ++it) {
        int task = tid + it * 256;
        int d = task >> 4, ch = task & 15;           // ch covers 2 64-key tiles
        short8 v = *(const short8*)&Vl[d][ch * 8];
        int pos = (ch & 7) ^ (d & 7);
        *(short8*)(dst + (size_t)d * NPIX + (ch & 8) * 8 + pos * 8) = v;
    }
}

// ---------------------------------------------------------------------------
// bf16 MFMA GEMM: C[M,N] = A[M,K] @ Bt[N,K]^T + bias (+Res) (+GELU)
// Operand-swapped MFMA (C^T tiles in regs) -> vectorized epilogue.
// OUTMODE: 0 = f32 row-major, 1 = bf16 row-major, 2 = f32 NCHW-transposed out.
// Double-buffered LDS, one barrier per K-step, XCD-swizzled linear grid.
// ---------------------------------------------------------------------------
template <int BN, int BK, int RES, int ACT, int OUTMODE>
__global__ __launch_bounds__(256) void gemm_bf16(
    const u16* __restrict__ A, const u16* __restrict__ Bt,
    const float* __restrict__ bias, const float* __restrict__ Res,
    void* __restrict__ Cout, int N, int K) {
    constexpr int KC = BK / 32;
    constexpr int NF = BN / 32;
    __shared__ u16 As[2][KC][128 * 32];
    __shared__ u16 Bs[2][KC][BN * 32];
    const int tid = threadIdx.x;
    const int lane = tid & 63;
    const int wv = tid >> 6;
    const int qd = lane >> 4;
    const int l16 = lane & 15;
    const int wy = wv >> 1, wx = wv & 1;

    const int id = blockIdx.x;
    const int xcd = id & 7, j = id >> 3;
    const int m0 = (xcd * 16 + (j & 15)) * 128;
    const int n0 = (j >> 4) * BN;

    const int rr = tid >> 2, cc = (tid & 3) * 8;
    const u16* Ag = A + (size_t)(m0 + rr) * K + cc;
    const u16* Bg = Bt + (size_t)(n0 + rr) * K + cc;

    const floatx4 fz = {0.f, 0.f, 0.f, 0.f};
    floatx4 acc[4][NF];
#pragma unroll
    for (int i = 0; i < 4; ++i)
#pragma unroll
        for (int jj = 0; jj < NF; ++jj) acc[i][jj] = fz;

    auto stage = [&](int slot, int k0) {
#pragma unroll
        for (int kc = 0; kc < KC; ++kc) {
            gl2lds16(Ag + k0 + kc * 32, &As[slot][kc][0] + tid * 8);
            gl2lds16(Ag + (size_t)64 * K + k0 + kc * 32, &As[slot][kc][0] + 2048 + tid * 8);
            gl2lds16(Bg + k0 + kc * 32, &Bs[slot][kc][0] + tid * 8);
            if (NF == 4) gl2lds16(Bg + (size_t)64 * K + k0 + kc * 32, &Bs[slot][kc][0] + 2048 + tid * 8);
        }
    };

    stage(0, 0);
    const int iters = K / BK;
    for (int it = 0; it < iters; ++it) {
        const int slot = it & 1;
        __syncthreads();
        if (it + 1 < iters) stage(slot ^ 1, (it + 1) * BK);
#pragma unroll
        for (int kc = 0; kc < KC; ++kc) {
            short8 af[4], bfr[NF];
#pragma unroll
            for (int i = 0; i < 4; ++i)
                af[i] = *(const short8*)(&As[slot][kc][0] + (wy * 64 + i * 16 + l16) * 32 + qd * 8);
#pragma unroll
            for (int jj = 0; jj < NF; ++jj)
                bfr[jj] = *(const short8*)(&Bs[slot][kc][0] + (wx * (BN / 2) + jj * 16 + l16) * 32 + qd * 8);
            // swapped operands: D = C^T tile; lane -> (col=qd*4+r, row=l16)
#pragma unroll
            for (int i = 0; i < 4; ++i)
#pragma unroll
                for (int jj = 0; jj < NF; ++jj) acc[i][jj] = MFMA16(bfr[jj], af[i], acc[i][jj]);
        }
    }

    const int rowb = m0 + wy * 64 + l16;
    const int colb = n0 + wx * (BN / 2) + qd * 4;
#pragma unroll
    for (int jj = 0; jj < NF; ++jj) {
        int col = colb + jj * 16;
        float4 bb = *(const float4*)(bias + col);
#pragma unroll
        for (int i = 0; i < 4; ++i) {
            int row = rowb + i * 16;
            floatx4 a = acc[i][jj];
            float v0 = a[0] + bb.x, v1 = a[1] + bb.y, v2 = a[2] + bb.z, v3 = a[3] + bb.w;
            if (RES) {
                float4 rv = *(const float4*)(Res + (size_t)row * N + col);
                v0 += rv.x; v1 += rv.y; v2 += rv.z; v3 += rv.w;
            }
            if (ACT) {
                v0 = 0.5f * v0 * (1.f + erff(v0 * 0.70710678118654752f));
                v1 = 0.5f * v1 * (1.f + erff(v1 * 0.70710678118654752f));
                v2 = 0.5f * v2 * (1.f + erff(v2 * 0.70710678118654752f));
                v3 = 0.5f * v3 * (1.f + erff(v3 * 0.70710678118654752f));
            }
            if (OUTMODE == 1) {
                uint2 pk;
                pk.x = pkbf(v0, v1);
                pk.y = pkbf(v2, v3);
                *(uint2*)((__hip_bfloat16*)Cout + (size_t)row * N + col) = pk;
            } else if (OUTMODE == 0) {
                float4 st = {v0, v1, v2, v3};
                *(float4*)((float*)Cout + (size_t)row * N + col) = st;
            } else {
                // NCHW: out[b][c][p]; lane holds 4 consecutive channels at pixel row
                int b_ = row >> 10, p = row & 1023;
                float* op = (float*)Cout + ((size_t)(b_ * CDIM + col)) * NPIX + p;
                op[0] = v0;
                op[NPIX] = v1;
                op[2 * NPIX] = v2;
                op[3 * NPIX] = v3;
            }
        }
    }
}

// ---------------------------------------------------------------------------
// MFMA flash attention: S^T = MFMA(K,Q), O^T = MFMA(V,P^T); no-max exp2 softmax,
// deferred normalization. SINGLE barrier per stage: K and V both staged via
// global_load_lds into double buffers (prefetch issued right after barrier).
// V global layout is XOR-swizzled so the linear LDS image is bank-optimal.
// ---------------------------------------------------------------------------
__global__ __launch_bounds__(256) void attn_kernel(const u16* __restrict__ qkv,
                                                   const u16* __restrict__ vT,
                                                   __hip_bfloat16* __restrict__ ob) {
    const int id = blockIdx.x;
    const int h = id & 7;
    const int b = (id >> 3) & 15;
    const int qb = id >> 7;
    const int tid = threadIdx.x;
    const int lane = tid & 63, wv = tid >> 6;
    const int qd = lane >> 4, l16 = lane & 15;

    __shared__ u16 Kl[2][65 * 48];               // dbuf [key][d] + safety row
    __shared__ u16 Vt[2][48 * 64];               // dbuf [d][key], swizzled image
    __shared__ __align__(16) u16 Plt[4][16 * 72];  // per-wave P^T [query][key]

    const size_t bh = (size_t)b * NPIX * QKVN + (size_t)h * DH;
    const u16* vtb = vT + (size_t)(b * NHEADS + h) * DH * NPIX;

    auto stageK = [&](int kt, int slot) {
        const size_t kbase = bh + (size_t)(kt * 64) * QKVN + CDIM;
        int key = tid / 6, ch = tid - key * 6;
        gl2lds16(qkv + kbase + (size_t)key * QKVN + ch * 8, &Kl[slot][0] + tid * 8);
        if (tid < 128) {
            int t2 = tid + 256;
            int k2 = t2 / 6, c2 = t2 - k2 * 6;
            gl2lds16(qkv + kbase + (size_t)k2 * QKVN + c2 * 8, &Kl[slot][0] + t2 * 8);
        }
    };
    auto stageV = [&](int kt, int slot) {
        const u16* vbase = vtb + (size_t)kt * 64 + (tid & 7) * 8;
        gl2lds16(vbase + (size_t)(tid >> 3) * NPIX, &Vt[slot][0] + tid * 8);
        if (tid < 128)
            gl2lds16(vbase + (size_t)((tid + 256) >> 3) * NPIX, &Vt[slot][0] + (tid + 256) * 8);
    };

    // Q fragments (B-operand), k padded 48->64 with zeros; scale*log2e folded in
    const float qsc = 0.14433756729740643f * 1.4426950408889634f;
    short8 qf[2][2];
    const short8 z8 = {0, 0, 0, 0, 0, 0, 0, 0};
#pragma unroll
    for (int g = 0; g < 2; ++g) {
        const u16* gq = qkv + bh + (size_t)(qb * 128 + wv * 32 + g * 16 + l16) * QKVN;
        short8 q0 = *(const short8*)(gq + qd * 8);
        short8 q1 = (qd < 2) ? *(const short8*)(gq + 32 + qd * 8) : z8;
#pragma unroll
        for (int e = 0; e < 8; ++e) {
            q0[e] = (short)f2bf(bf2f((u16)q0[e]) * qsc);
            q1[e] = (short)f2bf(bf2f((u16)q1[e]) * qsc);
        }
        qf[g][0] = q0;
        qf[g][1] = q1;
    }

    const floatx4 fz = {0.f, 0.f, 0.f, 0.f};
    floatx4 o[2][3];
    float lsum[2] = {0.f, 0.f};
#pragma unroll
    for (int g = 0; g < 2; ++g)
#pragma unroll
        for (int nt = 0; nt < 3; ++nt) o[g][nt] = fz;

    stageK(0, 0);
    stageV(0, 0);
    const int sw = l16 & 7;

    for (int kt = 0; kt < 16; ++kt) {
        const int cur = kt & 1;
        __syncthreads();  // drains stage(kt); all waves done reading buffers kt-2
        if (kt + 1 < 16) { stageK(kt + 1, cur ^ 1); stageV(kt + 1, cur ^ 1); }

        // K fragments (A-operand: m=key); overread d>=48 multiplied by qf1=0
        short8 kl[4], kh[4];
#pragma unroll
        for (int t = 0; t < 4; ++t) {
            const u16* kr = &Kl[cur][0] + (t * 16 + l16) * 48;
            kl[t] = *(const short8*)(kr + qd * 8);
            kh[t] = *(const short8*)(kr + 32 + qd * 8);
        }
        // V fragments (A-operand for PV: m=d); swizzled chunk position
        short8 vl[3], vh[3];
#pragma unroll
        for (int nt = 0; nt < 3; ++nt) {
            const u16* vr = &Vt[cur][0] + (nt * 16 + l16) * 64;
            vl[nt] = *(const short8*)(vr + (qd ^ sw) * 8);
            vh[nt] = *(const short8*)(vr + ((qd + 4) ^ sw) * 8);
        }

#pragma unroll
        for (int g = 0; g < 2; ++g) {
            // S^T tiles: lane -> (key = t*16+qd*4+r, query = l16)
#pragma unroll
            for (int t = 0; t < 4; ++t) {
                floatx4 a = fz;
                a = MFMA16(kl[t], qf[g][0], a);
                a = MFMA16(kh[t], qf[g][1], a);
                float p0 = __builtin_amdgcn_exp2f(a[0]);
                float p1 = __builtin_amdgcn_exp2f(a[1]);
                float p2 = __builtin_amdgcn_exp2f(a[2]);
                float p3 = __builtin_amdgcn_exp2f(a[3]);
                lsum[g] += (p0 + p1) + (p2 + p3);
                uint2 w;
                w.x = pkbf(p0, p1);
                w.y = pkbf(p2, p3);
                *(uint2*)&Plt[wv][l16 * 72 + t * 16 + qd * 4] = w;  // P^T[query][key]
            }
            // PV: O^T accumulate (B-operand = P^T read back, same-wave RAW)
            short8 ap0 = *(const short8*)&Plt[wv][l16 * 72 + qd * 8];
            short8 ap1 = *(const short8*)&Plt[wv][l16 * 72 + 32 + qd * 8];
#pragma unroll
            for (int nt = 0; nt < 3; ++nt) {
                o[g][nt] = MFMA16(vl[nt], ap0, o[g][nt]);
                o[g][nt] = MFMA16(vh[nt], ap1, o[g][nt]);
            }
        }
    }

    // epilogue: lane holds O^T[d=nt*16+qd*4+r][query=l16] -> 3 b64 stores per g
#pragma unroll
    for (int g = 0; g < 2; ++g) {
        float l = lsum[g];
        l += __shfl_xor(l, 16, 64);
        l += __shfl_xor(l, 32, 64);
        float inv = 1.f / l;
        __hip_bfloat16* orow =
            ob + (size_t)(b * NPIX + qb * 128 + wv * 32 + g * 16 + l16) * CDIM + h * DH;
#pragma unroll
        for (int nt = 0; nt < 3; ++nt) {
            float v0 = o[g][nt][0] * inv, v1 = o[g][nt][1] * inv;
            float v2 = o[g][nt][2] * inv, v3 = o[g][nt][3] * inv;
            uint2 w;
            w.x = pkbf(v0, v1);
            w.y = pkbf(v2, v3);
            *(uint2*)(orow + nt * 16 + qd * 4) = w;
        }
    }
}

// ---------------------------------------------------------------------------
extern "C" void kernel_launch(void* const* d_in, const int* in_sizes, int n_in,
                              void* d_out, int out_size, void* d_ws, size_t ws_size,
                              hipStream_t stream) {
    const float* x = (const float*)d_in[0];
    const float* pos_w = (const float*)d_in[1];
    const float* pos_b = (const float*)d_in[2];
    const float* g1 = (const float*)d_in[3];
    const float* b1 = (const float*)d_in[4];
    const float* wqkv = (const float*)d_in[5];
    const float* bqkv = (const float*)d_in[6];
    const float* wproj = (const float*)d_in[7];
    const float* bproj = (const float*)d_in[8];
    const float* g2 = (const float*)d_in[9];
    const float* b2 = (const float*)d_in[10];
    const float* w1 = (const float*)d_in[11];
    const float* bf1 = (const float*)d_in[12];
    const float* w2 = (const float*)d_in[13];
    const float* bf2 = (const float*)d_in[14];
    float* out = (float*)d_out;

    char* ws = (char*)d_ws;
    float* t = (float*)ws;
    __hip_bfloat16* xn = (__hip_bfloat16*)(ws + 25165824);
    u16* vTb = (u16*)xn;  // vT reuses xn (xn dead after qkv GEMM, vT dead before LN2)
    __hip_bfloat16* wqkvT = (__hip_bfloat16*)(ws + 37748736);
    __hip_bfloat16* wprojT = (__hip_bfloat16*)(ws + 38633472);
    __hip_bfloat16* w1T = (__hip_bfloat16*)(ws + 38928384);
    __hip_bfloat16* w2T = (__hip_bfloat16*)(ws + 40108032);
    char* big = ws + 41287680;
    u16* qkvb = (u16*)big;
    __hip_bfloat16* obb = (__hip_bfloat16*)(big + 37748736);
    u16* hb = (u16*)big;

    wt_all_kernel<<<dim3(1728), 256, 0, stream>>>(wqkv, wproj, w1, w2,
                                                  wqkvT, wprojT, w1T, w2T);
    conv_pe_kernel<<<dim3(CDIM / 64, HH, BATCH), 256, 0, stream>>>(x, pos_w, pos_b, t);
    ln_kernel<<<MTOK, 128, 0, stream>>>(t, g1, b1, xn);
    gemm_bf16<128, 32, 0, 0, 1><<<dim3(128 * (QKVN / 128)), 256, 0, stream>>>(
        (const u16*)xn, (const u16*)wqkvT, bqkv, nullptr, qkvb, QKVN, CDIM);
    vtrans_kernel<<<dim3(NPIX / 128, NHEADS, BATCH), 256, 0, stream>>>(qkvb, vTb);
    attn_kernel<<<dim3(1024), 256, 0, stream>>>(qkvb, vTb, obb);
    gemm_bf16<64, 64, 1, 0, 0><<<dim3(128 * (CDIM / 64)), 256, 0, stream>>>(
        (const u16*)obb, (const u16*)wprojT, bproj, t, t, CDIM, CDIM);
    ln_kernel<<<MTOK, 128, 0, stream>>>(t, g2, b2, xn);
    gemm_bf16<128, 32, 0, 1, 1><<<dim3(128 * (FFN / 128)), 256, 0, stream>>>(
        (const u16*)xn, (const u16*)w1T, bf1, nullptr, hb, FFN, CDIM);
    // mlp2 writes the NCHW output directly (residual from t, transposed store)
    gemm_bf16<64, 64, 1, 0, 2><<<dim3(128 * (CDIM / 64)), 256, 0, stream>>>(
        (const u16*)hb, (const u16*)w2T, bf2, t, out, CDIM, FFN);
}